// Round 11
// baseline (101.318 us; speedup 1.0000x reference)
//
#include <hip/hip_runtime.h>
#include <math.h>

#define BB 4
#define NN 8192
#define MM 8192
#define KK 16

// byte offsets for scratch regions
#define WS_CVB_BYTE  2048                        // 64*1024 ush = 131072 B
#define WS_XT_BYTE   (WS_CVB_BYTE + 131072)      // 4*8192*64 ush = 4194304 B
#define WS_PT_BYTE   (WS_XT_BYTE + 4194304)      // 4*8192*4 f32 = 524288 B
#define WS_MOMP_BYTE (WS_PT_BYTE + 524288)       // 128 blk * 12 f32 = 6144 B
#define WS_P2_BYTE   (WS_MOMP_BYTE + 6144)       // 512 blk * 32 f32 = 65536 B
#define WS_SB_BYTE   (WS_P2_BYTE + 65536)        // 4 * 64 f32 = 1024 B
#define WS_M3_BYTE   (WS_SB_BYTE + 1024)         // 4*8192*256 ush = 16777216 B

#define OV_STRIDE 1040   // ushorts per point

typedef __bf16 bhalf;
typedef bhalf bhalf8 __attribute__((ext_vector_type(8)));
typedef float f32x4 __attribute__((ext_vector_type(4)));
typedef ushort ushort8v __attribute__((ext_vector_type(8)));
typedef ushort ushort4v __attribute__((ext_vector_type(4)));

static __device__ __forceinline__ ushort f2b(float f) {
    return __builtin_bit_cast(ushort, (__bf16)f);   // v_cvt RNE, 1 op
}

// ---- DPP row reductions (16-lane rows), VALU-only: row_ror 1,2,4,8 ----
template <int CTRL>
__device__ __forceinline__ float dpp_rot(float v) {
    int r = __builtin_amdgcn_update_dpp(0, __builtin_bit_cast(int, v), CTRL, 0xF, 0xF, true);
    return __builtin_bit_cast(float, r);
}
__device__ __forceinline__ float gmax16(float v) {
    v = fmaxf(v, dpp_rot<0x121>(v));
    v = fmaxf(v, dpp_rot<0x122>(v));
    v = fmaxf(v, dpp_rot<0x124>(v));
    v = fmaxf(v, dpp_rot<0x128>(v));
    return v;
}
__device__ __forceinline__ float gsum16(float v) {
    v += dpp_rot<0x121>(v);
    v += dpp_rot<0x122>(v);
    v += dpp_rot<0x124>(v);
    v += dpp_rot<0x128>(v);
    return v;
}

// ---------------- k_pre: xT transpose+bf16, posT, cvb, moment partials ----------------
__global__ __launch_bounds__(256) void k_pre(const float* __restrict__ x,
                                             const float* __restrict__ pos,
                                             const float* __restrict__ sup,
                                             const int* __restrict__ nbr,
                                             const float* __restrict__ cv,
                                             float* __restrict__ momp,
                                             ushort* __restrict__ cvb,
                                             ushort* __restrict__ xT,
                                             float* __restrict__ posT) {
    int bid = blockIdx.x, t = threadIdx.x;
    if (bid < 512) {
        int b = bid >> 7, n0 = (bid & 127) * 64;
        __shared__ ushort tile[64 * 66];
        const float* xb = x + (size_t)b * 64 * NN;
#pragma unroll
        for (int i = 0; i < 16; i++) {
            int c = i * 4 + (t >> 6), n = t & 63;
            tile[c * 66 + n] = f2b(xb[(size_t)c * NN + n0 + n]);
        }
        __syncthreads();
#pragma unroll
        for (int i = 0; i < 16; i++) {
            int n = i * 4 + (t >> 6), c = t & 63;
            xT[((size_t)b * NN + n0 + n) * 64 + c] = tile[c * 66 + n];
        }
        int nl = t >> 2, d = t & 3;
        float v = (d < 3) ? pos[((size_t)b * 3 + d) * NN + n0 + nl] : 0.f;
        posT[((size_t)b * NN + n0 + nl) * 4 + d] = v;
    } else if (bid < 576) {
        int e = (bid - 512) * 1024 + t * 4;
        float4 cvv = *(const float4*)(cv + e);
        ushort4v o = {f2b(cvv.x), f2b(cvv.y), f2b(cvv.z), f2b(cvv.w)};
        *(ushort4v*)(cvb + e) = o;
    } else {
        __shared__ float redm[36];
        int rem = bid - 576;
        int b = rem & 3, m = (rem >> 2) * 256 + t;
        const float* posb = pos + (size_t)b * 3 * NN;
        float sx = sup[((size_t)b * 3 + 0) * MM + m];
        float sy = sup[((size_t)b * 3 + 1) * MM + m];
        float sz = sup[((size_t)b * 3 + 2) * MM + m];
        const int* nb = nbr + ((size_t)b * MM + m) * KK;
        float s[9] = {0, 0, 0, 0, 0, 0, 0, 0, 0};
#pragma unroll
        for (int k = 0; k < KK; k++) {
            int id = nb[k];
            float px = posb[id] - sx, py = posb[NN + id] - sy, pz = posb[2 * NN + id] - sz;
            s[0] += px; s[1] += py; s[2] += pz;
            s[3] += px * px; s[4] += py * py; s[5] += pz * pz;
            s[6] += px * py; s[7] += px * pz; s[8] += py * pz;
        }
#pragma unroll
        for (int i = 0; i < 9; i++) {
            float v = s[i];
#pragma unroll
            for (int off = 32; off >= 1; off >>= 1) v += __shfl_down(v, off);
            if ((t & 63) == 0) redm[(t >> 6) * 9 + i] = v;
        }
        __syncthreads();
        if (t < 9) momp[rem * 12 + t] = redm[t] + redm[9 + t] + redm[18 + t] + redm[27 + t];
    }
}

// ---------------- k_stats2: per-(b,c) stats partials, zero atomics, scalar weights ----
__global__ __launch_bounds__(256) void k_stats2(const float* __restrict__ sup,
                                                const int* __restrict__ nbr,
                                                const float* __restrict__ alpha_,
                                                const float* __restrict__ beta_,
                                                const float* __restrict__ nr_,
                                                const float* __restrict__ fc1,
                                                const float* __restrict__ fc2,
                                                const float* __restrict__ bn1w,
                                                const float* __restrict__ bn1b,
                                                const float* __restrict__ posT,
                                                const float* __restrict__ momp,
                                                float* __restrict__ p2) {
    __shared__ float sc1[16], bi1[16], momr[9], red[4 * 33];
    int t = threadIdx.x, b = blockIdx.y;
    if (t < 9) {
        float s = 0.f;
#pragma unroll
        for (int g = 0; g < 32; g++) s += momp[(4 * g + b) * 12 + t];
        momr[t] = s;
    }
    __syncthreads();
    if (t < 16) {
        float inv = 1.f / (float)(MM * KK);
        float inr = 1.f / nr_[0];
        float mux = momr[0] * inv * inr, muy = momr[1] * inv * inr, muz = momr[2] * inv * inr;
        float i2 = inv * inr * inr;
        float w0 = fc1[t * 3], w1v = fc1[t * 3 + 1], w2v = fc1[t * 3 + 2];
        float mean = w0 * mux + w1v * muy + w2v * muz;
        float ey2 = w0 * w0 * momr[3] * i2 + w1v * w1v * momr[4] * i2 + w2v * w2v * momr[5] * i2 +
                    2.f * (w0 * w1v * momr[6] * i2 + w0 * w2v * momr[7] * i2 + w1v * w2v * momr[8] * i2);
        float var = fmaxf(ey2 - mean * mean, 0.f);
        float rs = rsqrtf(var + 1e-5f);
        sc1[t] = bn1w[t] * rs;
        bi1[t] = bn1b[t] - mean * sc1[t];
    }
    __syncthreads();
    int mi = t >> 2, kq = t & 3;
    int m = blockIdx.x * 64 + mi;
    float alpha = alpha_[0], beta = beta_[0], inr = 1.f / nr_[0];
    float sx = sup[((size_t)b * 3 + 0) * MM + m];
    float sy = sup[((size_t)b * 3 + 1) * MM + m];
    float sz = sup[((size_t)b * 3 + 2) * MM + m];
    const int* nb = nbr + ((size_t)b * MM + m) * KK + kq * 4;

    float q1m[16], G1[16], G2[16];
#pragma unroll
    for (int j = 0; j < 16; j++) { q1m[j] = 0.f; G1[j] = 0.f; G2[j] = 0.f; }
    float S = 0.f;
#pragma unroll
    for (int kk = 0; kk < 4; kk++) {
        int id = nb[kk];
        float4 pv = *(const float4*)(posT + ((size_t)b * NN + id) * 4);
        float rx = pv.x - sx, ry = pv.y - sy, rz = pv.z - sz;
        float dd = sqrtf(rx * rx + ry * ry + rz * rz);
        float srk = 1.f / (1.f + expf(alpha * dd - beta));
        S += srk;
        float nxv = rx * inr, nyv = ry * inr, nzv = rz * inr;
        float m1c[16];
#pragma unroll
        for (int j = 0; j < 16; j++) {
            float y = fc1[j * 3] * nxv + fc1[j * 3 + 1] * nyv + fc1[j * 3 + 2] * nzv;
            m1c[j] = fmaxf(y * sc1[j] + bi1[j], 0.f);
            q1m[j] = fmaxf(q1m[j], m1c[j] * srk);
        }
#pragma unroll
        for (int c = 0; c < 16; c++) {
            float g = 0.f;
#pragma unroll
            for (int q = 0; q < 4; q++) {
                float4 v = *(const float4*)(fc2 + c * 32 + q * 4);     // uniform -> s_load
                g += v.x * m1c[q * 4] + v.y * m1c[q * 4 + 1] +
                     v.z * m1c[q * 4 + 2] + v.w * m1c[q * 4 + 3];
            }
            G1[c] += g; G2[c] += g * g;
        }
    }
    S += __shfl_xor(S, 1); S += __shfl_xor(S, 2);
#pragma unroll
    for (int j = 0; j < 16; j++) {
        q1m[j] = fmaxf(q1m[j], __shfl_xor(q1m[j], 1));
        q1m[j] = fmaxf(q1m[j], __shfl_xor(q1m[j], 2));
    }
    S = S + (S == 0.f ? 1.f : 0.f) + 1e-6f;
    float fac = 16.f / S;
#pragma unroll
    for (int c = 0; c < 16; c++) {
        float h2 = 0.f;
#pragma unroll
        for (int q = 0; q < 4; q++) {
            float4 v = *(const float4*)(fc2 + c * 32 + 16 + q * 4);    // uniform -> s_load
            h2 += v.x * q1m[q * 4] + v.y * q1m[q * 4 + 1] +
                  v.z * q1m[q * 4 + 2] + v.w * q1m[q * 4 + 3];
        }
        h2 *= fac;
        float s2p = G1[c] + 4.f * h2;
        float q2p = G2[c] + 2.f * h2 * G1[c] + 4.f * h2 * h2;
#pragma unroll
        for (int off = 32; off >= 1; off >>= 1) {
            s2p += __shfl_down(s2p, off);
            q2p += __shfl_down(q2p, off);
        }
        if ((t & 63) == 0) {
            red[(t >> 6) * 33 + c] = s2p;
            red[(t >> 6) * 33 + 16 + c] = q2p;
        }
    }
    __syncthreads();
    if (t < 32)
        p2[((size_t)b * 128 + blockIdx.x) * 32 + t] =
            red[t] + red[33 + t] + red[66 + t] + red[99 + t];
}

// ---------------- k_fin: final reduce momp/p2 -> s1,b1,s2,b2 per batch ----------------
__global__ __launch_bounds__(256) void k_fin(const float* __restrict__ momp,
                                             const float* __restrict__ p2,
                                             const float* __restrict__ fc1,
                                             const float* __restrict__ bn1w,
                                             const float* __restrict__ bn1b,
                                             const float* __restrict__ bn2w,
                                             const float* __restrict__ bn2b,
                                             const float* __restrict__ nr_,
                                             float* __restrict__ sb) {
    __shared__ float red[8 * 33], momr[9];
    int b = blockIdx.x, t = threadIdx.x;
    int c = t & 31, ch = t >> 5;
    float s = 0.f;
#pragma unroll
    for (int g = 0; g < 16; g++) s += p2[((size_t)b * 128 + ch * 16 + g) * 32 + c];
    red[ch * 33 + c] = s;
    if (t < 9) {
        float v = 0.f;
#pragma unroll
        for (int g = 0; g < 32; g++) v += momp[(4 * g + b) * 12 + t];
        momr[t] = v;
    }
    __syncthreads();
    if (t < 16) {
        float inv = 1.f / (float)(MM * KK);
        float inr = 1.f / nr_[0];
        float mux = momr[0] * inv * inr, muy = momr[1] * inv * inr, muz = momr[2] * inv * inr;
        float i2 = inv * inr * inr;
        float w0 = fc1[t * 3], wa = fc1[t * 3 + 1], wb = fc1[t * 3 + 2];
        float mean = w0 * mux + wa * muy + wb * muz;
        float ey2 = w0 * w0 * momr[3] * i2 + wa * wa * momr[4] * i2 + wb * wb * momr[5] * i2 +
                    2.f * (w0 * wa * momr[6] * i2 + w0 * wb * momr[7] * i2 + wa * wb * momr[8] * i2);
        float var = fmaxf(ey2 - mean * mean, 0.f);
        float rs = rsqrtf(var + 1e-5f);
        float s1v = bn1w[t] * rs;
        float b1v = bn1b[t] - mean * s1v;
        float sum2 = 0.f, ssq2 = 0.f;
#pragma unroll
        for (int chh = 0; chh < 8; chh++) {
            sum2 += red[chh * 33 + t];
            ssq2 += red[chh * 33 + 16 + t];
        }
        float mean2 = sum2 * inv;
        float var2 = fmaxf(ssq2 * inv - mean2 * mean2, 0.f);
        float rs2 = rsqrtf(var2 + 1e-5f);
        float s2v = bn2w[t] * rs2;
        float b2v = bn2b[t] - mean2 * s2v;
        sb[b * 64 + t] = s1v;
        sb[b * 64 + 16 + t] = b1v;
        sb[b * 64 + 32 + t] = s2v;
        sb[b * 64 + 48 + t] = b2v;
    }
}

// ---------------- k_mat3: phase 1 only, ZERO LDS, high occupancy ----------------
__global__ __launch_bounds__(256, 5) void k_mat3(const float* __restrict__ sup,
                                                 const int* __restrict__ nbr,
                                                 const float* __restrict__ alpha_,
                                                 const float* __restrict__ beta_,
                                                 const float* __restrict__ nr_,
                                                 const float* __restrict__ fc1,
                                                 const float* __restrict__ fc2,
                                                 const float* __restrict__ fc3,
                                                 const float* __restrict__ sb,
                                                 const float* __restrict__ posT,
                                                 ushort* __restrict__ m3g) {
    int t = threadIdx.x;
    int b = blockIdx.y;
    int m0 = blockIdx.x * 16;
    int l = t & 63;
    int ps = t >> 4, ks = t & 15;
    int mm = m0 + ps;

    int idxt = nbr[((size_t)b * MM + mm) * KK + ks];
    float4 pf = *(const float4*)(posT + ((size_t)b * NN + idxt) * 4);
    float4 w2b0 = *(const float4*)(fc2 + ks * 32 + 16);
    float4 w2b1 = *(const float4*)(fc2 + ks * 32 + 20);
    float4 w2b2 = *(const float4*)(fc2 + ks * 32 + 24);
    float4 w2b3 = *(const float4*)(fc2 + ks * 32 + 28);
    float4 w3b0 = *(const float4*)(fc3 + ks * 32 + 16);
    float4 w3b1 = *(const float4*)(fc3 + ks * 32 + 20);
    float4 w3b2 = *(const float4*)(fc3 + ks * 32 + 24);
    float4 w3b3 = *(const float4*)(fc3 + ks * 32 + 28);

    float alpha = alpha_[0], beta = beta_[0], inr = 1.f / nr_[0];
    const float* sbb = sb + b * 64;

    float rx = pf.x - sup[((size_t)b * 3 + 0) * MM + mm];
    float ry = pf.y - sup[((size_t)b * 3 + 1) * MM + mm];
    float rz = pf.z - sup[((size_t)b * 3 + 2) * MM + mm];
    float dd = sqrtf(rx * rx + ry * ry + rz * rz);
    float sr = 1.f / (1.f + expf(alpha * dd - beta));
    float S = gsum16(sr);
    S = S + (S == 0.f ? 1.f : 0.f) + 1e-6f;
    float dwk = sr * (16.f / S);
    float nxv = rx * inr, nyv = ry * inr, nzv = rz * inr;

    float m1v[16], mp1[16];
#pragma unroll
    for (int j = 0; j < 16; j++) {
        float y = fc1[j * 3] * nxv + fc1[j * 3 + 1] * nyv + fc1[j * 3 + 2] * nzv;
        m1v[j] = fmaxf(y * sbb[j] + sbb[16 + j], 0.f);
    }
#pragma unroll
    for (int j = 0; j < 16; j++) mp1[j] = gmax16(m1v[j] * dwk);

    float h2own = w2b0.x * mp1[0] + w2b0.y * mp1[1] + w2b0.z * mp1[2] + w2b0.w * mp1[3]
                + w2b1.x * mp1[4] + w2b1.y * mp1[5] + w2b1.z * mp1[6] + w2b1.w * mp1[7]
                + w2b2.x * mp1[8] + w2b2.y * mp1[9] + w2b2.z * mp1[10] + w2b2.w * mp1[11]
                + w2b3.x * mp1[12] + w2b3.y * mp1[13] + w2b3.z * mp1[14] + w2b3.w * mp1[15];
    int pbase = l & 48;
    float m2v[16], mp2[16];
#pragma unroll
    for (int c = 0; c < 16; c++) {
        float a = 0.f;
#pragma unroll
        for (int q = 0; q < 4; q++) {
            float4 v = *(const float4*)(fc2 + c * 32 + q * 4);     // uniform -> s_load
            a += v.x * m1v[q * 4] + v.y * m1v[q * 4 + 1] + v.z * m1v[q * 4 + 2] + v.w * m1v[q * 4 + 3];
        }
        a += __shfl(h2own, pbase + c);
        m2v[c] = fmaxf(a * sbb[32 + c] + sbb[48 + c], 0.f);
    }
#pragma unroll
    for (int c = 0; c < 16; c++) mp2[c] = gmax16(m2v[c] * dwk);

    float h3own = w3b0.x * mp2[0] + w3b0.y * mp2[1] + w3b0.z * mp2[2] + w3b0.w * mp2[3]
                + w3b1.x * mp2[4] + w3b1.y * mp2[5] + w3b1.z * mp2[6] + w3b1.w * mp2[7]
                + w3b2.x * mp2[8] + w3b2.y * mp2[9] + w3b2.z * mp2[10] + w3b2.w * mp2[11]
                + w3b3.x * mp2[12] + w3b3.y * mp2[13] + w3b3.z * mp2[14] + w3b3.w * mp2[15];
    ushort* m3p = m3g + ((size_t)b * MM + mm) * 256;
#pragma unroll
    for (int j = 0; j < 16; j++) {
        float a = 0.f;
#pragma unroll
        for (int q = 0; q < 4; q++) {
            float4 v = *(const float4*)(fc3 + j * 32 + q * 4);     // uniform -> s_load
            a += v.x * m2v[q * 4] + v.y * m2v[q * 4 + 1] + v.z * m2v[q * 4 + 2] + v.w * m2v[q * 4 + 3];
        }
        a += __shfl(h3own, pbase + j);
        m3p[j * 16 + ks] = f2b(fmaxf(a, 0.f) * dwk);
    }
}

// ---------------- k_gemm: staging + MFMA stages B/C; LDS = feat only ----------------
__global__ __launch_bounds__(256, 4) void k_gemm(const int* __restrict__ nbr,
                                                 const ushort* __restrict__ m3g,
                                                 const ushort* __restrict__ cvb,
                                                 const ushort* __restrict__ xT,
                                                 float* __restrict__ out) {
    __shared__ __align__(16) ushort ov[16 * OV_STRIDE]; // per point: xg[c][k], feat overlay

    int t = threadIdx.x;
    int b = blockIdx.y;
    int m0 = blockIdx.x * 16;
    int w = t >> 6, l = t & 63;
    int lk = l & 15, kg = l >> 4;
    int ps = t >> 4, ks = t & 15;

    // ---- staging loads ----
    int idxt = nbr[((size_t)b * MM + m0 + ps) * KK + ks];
    const ushort8v* xrow = (const ushort8v*)(xT + ((size_t)b * NN + idxt) * 64);
    ushort8v g0 = xrow[0], g1 = xrow[1], g2 = xrow[2], g3 = xrow[3];
    ushort8v g4 = xrow[4], g5 = xrow[5], g6 = xrow[6], g7 = xrow[7];

    // mat3 A-fragments for this wave's 4 points (coalesced global, independent of staging)
    ushort8v afrp[4];
#pragma unroll
    for (int pp = 0; pp < 4; pp++) {
        int p = w * 4 + pp;
        if (kg < 2)
            afrp[pp] = *(const ushort8v*)(m3g + ((size_t)b * MM + m0 + p) * 256 + lk * 16 + kg * 8);
        else
            afrp[pp] = (ushort8v){0, 0, 0, 0, 0, 0, 0, 0};
    }

    // ---- write staged xg rows: ov[p][c*16 + k]  (wave-local) ----
    {
        ushort* ovp = ov + ps * OV_STRIDE;
#define STG(gv, h) _Pragma("unroll") for (int i2 = 0; i2 < 8; i2++) ovp[((h) * 8 + i2) * 16 + ks] = (ushort)gv[i2];
        STG(g0, 0) STG(g1, 1) STG(g2, 2) STG(g3, 3)
        STG(g4, 4) STG(g5, 5) STG(g6, 6) STG(g7, 7)
#undef STG
    }
    // NO barrier: stage B touches only this wave's points

    const f32x4 zz = {0.f, 0.f, 0.f, 0.f};

    // ---- stage B (MFMA): feat[j][c] = sum_k mat3[j][k] * xg[c][k]; overlay onto ov ----
#pragma unroll
    for (int pp = 0; pp < 4; pp++) {
        int p = w * 4 + pp;
        bhalf8 afr = __builtin_bit_cast(bhalf8, afrp[pp]);
        ushort* ovb = ov + p * OV_STRIDE;
#pragma unroll
        for (int cb = 0; cb < 4; cb++) {
            bhalf8 bfr = {};
            if (kg < 2) bfr = __builtin_bit_cast(bhalf8, *(ushort8v*)(ovb + (cb * 16 + lk) * 16 + kg * 8));
            f32x4 dF = __builtin_amdgcn_mfma_f32_16x16x32_bf16(afr, bfr, zz, 0, 0, 0);
            ushort4v fw = {f2b(dF[0]), f2b(dF[1]), f2b(dF[2]), f2b(dF[3])};
            *(ushort4v*)(ovb + (cb * 16 + lk) * 16 + kg * 4) = fw;
        }
    }

    // ---- prefetch first 4 stage-C A-fragments ----
    const ushort* arow = cvb + (size_t)(w * 16 + lk) * 1024;
    ushort8v aupre0 = *(const ushort8v*)(arow + 0 * 32 + kg * 8);
    ushort8v aupre1 = *(const ushort8v*)(arow + 1 * 32 + kg * 8);
    ushort8v aupre2 = *(const ushort8v*)(arow + 2 * 32 + kg * 8);
    ushort8v aupre3 = *(const ushort8v*)(arow + 3 * 32 + kg * 8);

    __syncthreads();   // the ONE barrier: stage C reads all points' feat

    // ---- stage C (MFMA): out[o][p] = sum_cj cvb[o][cj] * feat[p][cj]; dual acc ----
    {
        const ushort* brow = ov + lk * OV_STRIDE;
        f32x4 acc0 = zz, acc1 = zz;
#pragma unroll
        for (int kt = 0; kt < 32; kt += 2) {
            bhalf8 au0, au1;
            if (kt == 0) {
                au0 = __builtin_bit_cast(bhalf8, aupre0);
                au1 = __builtin_bit_cast(bhalf8, aupre1);
            } else if (kt == 2) {
                au0 = __builtin_bit_cast(bhalf8, aupre2);
                au1 = __builtin_bit_cast(bhalf8, aupre3);
            } else {
                au0 = __builtin_bit_cast(bhalf8, *(const ushort8v*)(arow + kt * 32 + kg * 8));
                au1 = __builtin_bit_cast(bhalf8, *(const ushort8v*)(arow + (kt + 1) * 32 + kg * 8));
            }
            bhalf8 bu0 = __builtin_bit_cast(bhalf8, *(const ushort8v*)(brow + kt * 32 + kg * 8));
            bhalf8 bu1 = __builtin_bit_cast(bhalf8, *(const ushort8v*)(brow + (kt + 1) * 32 + kg * 8));
            acc0 = __builtin_amdgcn_mfma_f32_16x16x32_bf16(au0, bu0, acc0, 0, 0, 0);
            acc1 = __builtin_amdgcn_mfma_f32_16x16x32_bf16(au1, bu1, acc1, 0, 0, 0);
        }
#pragma unroll
        for (int r = 0; r < 4; r++) {
            int o = w * 16 + kg * 4 + r;
            out[((size_t)(b * 64 + o)) * MM + m0 + lk] = acc0[r] + acc1[r];
        }
    }
}

extern "C" void kernel_launch(void* const* d_in, const int* in_sizes, int n_in,
                              void* d_out, int out_size, void* d_ws, size_t ws_size,
                              hipStream_t stream) {
    const float* x    = (const float*)d_in[0];
    const float* pos  = (const float*)d_in[1];
    const float* sup  = (const float*)d_in[2];
    const int*   nbr  = (const int*)d_in[3];
    const float* alp  = (const float*)d_in[4];
    const float* bet  = (const float*)d_in[5];
    const float* nr   = (const float*)d_in[6];
    const float* fc1  = (const float*)d_in[7];
    const float* fc2  = (const float*)d_in[8];
    const float* fc3  = (const float*)d_in[9];
    const float* bn1w = (const float*)d_in[10];
    const float* bn1b = (const float*)d_in[11];
    const float* bn2w = (const float*)d_in[12];
    const float* bn2b = (const float*)d_in[13];
    const float* cv   = (const float*)d_in[14];
    float* out = (float*)d_out;
    ushort* cvb  = (ushort*)((char*)d_ws + WS_CVB_BYTE);
    ushort* xT   = (ushort*)((char*)d_ws + WS_XT_BYTE);
    float*  posT = (float*)((char*)d_ws + WS_PT_BYTE);
    float*  momp = (float*)((char*)d_ws + WS_MOMP_BYTE);
    float*  p2   = (float*)((char*)d_ws + WS_P2_BYTE);
    float*  sb   = (float*)((char*)d_ws + WS_SB_BYTE);
    ushort* m3g  = (ushort*)((char*)d_ws + WS_M3_BYTE);

    k_pre<<<704, 256, 0, stream>>>(x, pos, sup, nbr, cv, momp, cvb, xT, posT);
    k_stats2<<<dim3(128, BB), 256, 0, stream>>>(sup, nbr, alp, bet, nr, fc1, fc2,
                                                bn1w, bn1b, posT, momp, p2);
    k_fin<<<BB, 256, 0, stream>>>(momp, p2, fc1, bn1w, bn1b, bn2w, bn2b, nr, sb);
    k_mat3<<<dim3(512, BB), 256, 0, stream>>>(sup, nbr, alp, bet, nr, fc1, fc2, fc3,
                                              sb, posT, m3g);
    k_gemm<<<dim3(512, BB), 256, 0, stream>>>(nbr, m3g, cvb, xT, out);
}

// Round 12
// 96.820 us; speedup vs baseline: 1.0465x; 1.0465x over previous
//
#include <hip/hip_runtime.h>
#include <math.h>

#define BB 4
#define NN 8192
#define MM 8192
#define KK 16

// byte offsets for scratch regions
#define WS_CVB_BYTE  2048                        // 64*1024 ush = 131072 B
#define WS_XT_BYTE   (WS_CVB_BYTE + 131072)      // 4*8192*64 ush = 4194304 B
#define WS_PT_BYTE   (WS_XT_BYTE + 4194304)      // 4*8192*4 f32 = 524288 B
#define WS_MOMP_BYTE (WS_PT_BYTE + 524288)       // 128 blk * 12 f32 = 6144 B
#define WS_P2_BYTE   (WS_MOMP_BYTE + 6144)       // 512 blk * 32 f32 = 65536 B
#define WS_SB_BYTE   (WS_P2_BYTE + 65536)        // 4 * 64 f32 = 1024 B

#define OV_STRIDE 1032   // 516 dw = 4 mod 32 -> stage-C lane starts tile banks perfectly
#define M3_STRIDE 384
#define TPB 4            // tiles (of 16 points) per persistent block

typedef __bf16 bhalf;
typedef bhalf bhalf8 __attribute__((ext_vector_type(8)));
typedef float f32x4 __attribute__((ext_vector_type(4)));
typedef ushort ushort8v __attribute__((ext_vector_type(8)));
typedef ushort ushort4v __attribute__((ext_vector_type(4)));

static __device__ __forceinline__ ushort f2b(float f) {
    return __builtin_bit_cast(ushort, (__bf16)f);
}

// ---- DPP row reductions (16-lane rows), VALU-only: row_ror 1,2,4,8 ----
template <int CTRL>
__device__ __forceinline__ float dpp_rot(float v) {
    int r = __builtin_amdgcn_update_dpp(0, __builtin_bit_cast(int, v), CTRL, 0xF, 0xF, true);
    return __builtin_bit_cast(float, r);
}
__device__ __forceinline__ float gmax16(float v) {
    v = fmaxf(v, dpp_rot<0x121>(v));
    v = fmaxf(v, dpp_rot<0x122>(v));
    v = fmaxf(v, dpp_rot<0x124>(v));
    v = fmaxf(v, dpp_rot<0x128>(v));
    return v;
}
__device__ __forceinline__ float gsum16(float v) {
    v += dpp_rot<0x121>(v);
    v += dpp_rot<0x122>(v);
    v += dpp_rot<0x124>(v);
    v += dpp_rot<0x128>(v);
    return v;
}

// ---------------- k_pre: xT transpose+bf16, posT, cvb, moment partials ----------------
__global__ __launch_bounds__(256) void k_pre(const float* __restrict__ x,
                                             const float* __restrict__ pos,
                                             const float* __restrict__ sup,
                                             const int* __restrict__ nbr,
                                             const float* __restrict__ cv,
                                             float* __restrict__ momp,
                                             ushort* __restrict__ cvb,
                                             ushort* __restrict__ xT,
                                             float* __restrict__ posT) {
    int bid = blockIdx.x, t = threadIdx.x;
    if (bid < 512) {
        int b = bid >> 7, n0 = (bid & 127) * 64;
        __shared__ ushort tile[64 * 66];
        const float* xb = x + (size_t)b * 64 * NN;
#pragma unroll
        for (int i = 0; i < 16; i++) {
            int c = i * 4 + (t >> 6), n = t & 63;
            tile[c * 66 + n] = f2b(xb[(size_t)c * NN + n0 + n]);
        }
        __syncthreads();
#pragma unroll
        for (int i = 0; i < 16; i++) {
            int n = i * 4 + (t >> 6), c = t & 63;
            xT[((size_t)b * NN + n0 + n) * 64 + c] = tile[c * 66 + n];
        }
        int nl = t >> 2, d = t & 3;
        float v = (d < 3) ? pos[((size_t)b * 3 + d) * NN + n0 + nl] : 0.f;
        posT[((size_t)b * NN + n0 + nl) * 4 + d] = v;
    } else if (bid < 576) {
        int e = (bid - 512) * 1024 + t * 4;
        float4 cvv = *(const float4*)(cv + e);
        ushort4v o = {f2b(cvv.x), f2b(cvv.y), f2b(cvv.z), f2b(cvv.w)};
        *(ushort4v*)(cvb + e) = o;
    } else {
        __shared__ float redm[36];
        int rem = bid - 576;
        int b = rem & 3, m = (rem >> 2) * 256 + t;
        const float* posb = pos + (size_t)b * 3 * NN;
        float sx = sup[((size_t)b * 3 + 0) * MM + m];
        float sy = sup[((size_t)b * 3 + 1) * MM + m];
        float sz = sup[((size_t)b * 3 + 2) * MM + m];
        const int* nb = nbr + ((size_t)b * MM + m) * KK;
        float s[9] = {0, 0, 0, 0, 0, 0, 0, 0, 0};
#pragma unroll
        for (int k = 0; k < KK; k++) {
            int id = nb[k];
            float px = posb[id] - sx, py = posb[NN + id] - sy, pz = posb[2 * NN + id] - sz;
            s[0] += px; s[1] += py; s[2] += pz;
            s[3] += px * px; s[4] += py * py; s[5] += pz * pz;
            s[6] += px * py; s[7] += px * pz; s[8] += py * pz;
        }
#pragma unroll
        for (int i = 0; i < 9; i++) {
            float v = s[i];
#pragma unroll
            for (int off = 32; off >= 1; off >>= 1) v += __shfl_down(v, off);
            if ((t & 63) == 0) redm[(t >> 6) * 9 + i] = v;
        }
        __syncthreads();
        if (t < 9) momp[rem * 12 + t] = redm[t] + redm[9 + t] + redm[18 + t] + redm[27 + t];
    }
}

// ---------------- k_stats2: per-(b,c) stats partials, zero atomics, scalar weights ----
__global__ __launch_bounds__(256) void k_stats2(const float* __restrict__ sup,
                                                const int* __restrict__ nbr,
                                                const float* __restrict__ alpha_,
                                                const float* __restrict__ beta_,
                                                const float* __restrict__ nr_,
                                                const float* __restrict__ fc1,
                                                const float* __restrict__ fc2,
                                                const float* __restrict__ bn1w,
                                                const float* __restrict__ bn1b,
                                                const float* __restrict__ posT,
                                                const float* __restrict__ momp,
                                                float* __restrict__ p2) {
    __shared__ float sc1[16], bi1[16], momr[9], red[4 * 33];
    int t = threadIdx.x, b = blockIdx.y;
    if (t < 9) {
        float s = 0.f;
#pragma unroll
        for (int g = 0; g < 32; g++) s += momp[(4 * g + b) * 12 + t];
        momr[t] = s;
    }
    __syncthreads();
    if (t < 16) {
        float inv = 1.f / (float)(MM * KK);
        float inr = 1.f / nr_[0];
        float mux = momr[0] * inv * inr, muy = momr[1] * inv * inr, muz = momr[2] * inv * inr;
        float i2 = inv * inr * inr;
        float w0 = fc1[t * 3], w1v = fc1[t * 3 + 1], w2v = fc1[t * 3 + 2];
        float mean = w0 * mux + w1v * muy + w2v * muz;
        float ey2 = w0 * w0 * momr[3] * i2 + w1v * w1v * momr[4] * i2 + w2v * w2v * momr[5] * i2 +
                    2.f * (w0 * w1v * momr[6] * i2 + w0 * w2v * momr[7] * i2 + w1v * w2v * momr[8] * i2);
        float var = fmaxf(ey2 - mean * mean, 0.f);
        float rs = rsqrtf(var + 1e-5f);
        sc1[t] = bn1w[t] * rs;
        bi1[t] = bn1b[t] - mean * sc1[t];
    }
    __syncthreads();
    int mi = t >> 2, kq = t & 3;
    int m = blockIdx.x * 64 + mi;
    float alpha = alpha_[0], beta = beta_[0], inr = 1.f / nr_[0];
    float sx = sup[((size_t)b * 3 + 0) * MM + m];
    float sy = sup[((size_t)b * 3 + 1) * MM + m];
    float sz = sup[((size_t)b * 3 + 2) * MM + m];
    const int* nb = nbr + ((size_t)b * MM + m) * KK + kq * 4;

    float q1m[16], G1[16], G2[16];
#pragma unroll
    for (int j = 0; j < 16; j++) { q1m[j] = 0.f; G1[j] = 0.f; G2[j] = 0.f; }
    float S = 0.f;
#pragma unroll
    for (int kk = 0; kk < 4; kk++) {
        int id = nb[kk];
        float4 pv = *(const float4*)(posT + ((size_t)b * NN + id) * 4);
        float rx = pv.x - sx, ry = pv.y - sy, rz = pv.z - sz;
        float dd = sqrtf(rx * rx + ry * ry + rz * rz);
        float srk = 1.f / (1.f + expf(alpha * dd - beta));
        S += srk;
        float nxv = rx * inr, nyv = ry * inr, nzv = rz * inr;
        float m1c[16];
#pragma unroll
        for (int j = 0; j < 16; j++) {
            float y = fc1[j * 3] * nxv + fc1[j * 3 + 1] * nyv + fc1[j * 3 + 2] * nzv;
            m1c[j] = fmaxf(y * sc1[j] + bi1[j], 0.f);
            q1m[j] = fmaxf(q1m[j], m1c[j] * srk);
        }
#pragma unroll
        for (int c = 0; c < 16; c++) {
            float g = 0.f;
#pragma unroll
            for (int q = 0; q < 4; q++) {
                float4 v = *(const float4*)(fc2 + c * 32 + q * 4);
                g += v.x * m1c[q * 4] + v.y * m1c[q * 4 + 1] +
                     v.z * m1c[q * 4 + 2] + v.w * m1c[q * 4 + 3];
            }
            G1[c] += g; G2[c] += g * g;
        }
    }
    S += __shfl_xor(S, 1); S += __shfl_xor(S, 2);
#pragma unroll
    for (int j = 0; j < 16; j++) {
        q1m[j] = fmaxf(q1m[j], __shfl_xor(q1m[j], 1));
        q1m[j] = fmaxf(q1m[j], __shfl_xor(q1m[j], 2));
    }
    S = S + (S == 0.f ? 1.f : 0.f) + 1e-6f;
    float fac = 16.f / S;
#pragma unroll
    for (int c = 0; c < 16; c++) {
        float h2 = 0.f;
#pragma unroll
        for (int q = 0; q < 4; q++) {
            float4 v = *(const float4*)(fc2 + c * 32 + 16 + q * 4);
            h2 += v.x * q1m[q * 4] + v.y * q1m[q * 4 + 1] +
                  v.z * q1m[q * 4 + 2] + v.w * q1m[q * 4 + 3];
        }
        h2 *= fac;
        float s2p = G1[c] + 4.f * h2;
        float q2p = G2[c] + 2.f * h2 * G1[c] + 4.f * h2 * h2;
#pragma unroll
        for (int off = 32; off >= 1; off >>= 1) {
            s2p += __shfl_down(s2p, off);
            q2p += __shfl_down(q2p, off);
        }
        if ((t & 63) == 0) {
            red[(t >> 6) * 33 + c] = s2p;
            red[(t >> 6) * 33 + 16 + c] = q2p;
        }
    }
    __syncthreads();
    if (t < 32)
        p2[((size_t)b * 128 + blockIdx.x) * 32 + t] =
            red[t] + red[33 + t] + red[66 + t] + red[99 + t];
}

// ---------------- k_fin: final reduce momp/p2 -> s1,b1,s2,b2 per batch ----------------
__global__ __launch_bounds__(256) void k_fin(const float* __restrict__ momp,
                                             const float* __restrict__ p2,
                                             const float* __restrict__ fc1,
                                             const float* __restrict__ bn1w,
                                             const float* __restrict__ bn1b,
                                             const float* __restrict__ bn2w,
                                             const float* __restrict__ bn2b,
                                             const float* __restrict__ nr_,
                                             float* __restrict__ sb) {
    __shared__ float red[8 * 33], momr[9];
    int b = blockIdx.x, t = threadIdx.x;
    int c = t & 31, ch = t >> 5;
    float s = 0.f;
#pragma unroll
    for (int g = 0; g < 16; g++) s += p2[((size_t)b * 128 + ch * 16 + g) * 32 + c];
    red[ch * 33 + c] = s;
    if (t < 9) {
        float v = 0.f;
#pragma unroll
        for (int g = 0; g < 32; g++) v += momp[(4 * g + b) * 12 + t];
        momr[t] = v;
    }
    __syncthreads();
    if (t < 16) {
        float inv = 1.f / (float)(MM * KK);
        float inr = 1.f / nr_[0];
        float mux = momr[0] * inv * inr, muy = momr[1] * inv * inr, muz = momr[2] * inv * inr;
        float i2 = inv * inr * inr;
        float w0 = fc1[t * 3], wa = fc1[t * 3 + 1], wb = fc1[t * 3 + 2];
        float mean = w0 * mux + wa * muy + wb * muz;
        float ey2 = w0 * w0 * momr[3] * i2 + wa * wa * momr[4] * i2 + wb * wb * momr[5] * i2 +
                    2.f * (w0 * wa * momr[6] * i2 + w0 * wb * momr[7] * i2 + wa * wb * momr[8] * i2);
        float var = fmaxf(ey2 - mean * mean, 0.f);
        float rs = rsqrtf(var + 1e-5f);
        float s1v = bn1w[t] * rs;
        float b1v = bn1b[t] - mean * s1v;
        float sum2 = 0.f, ssq2 = 0.f;
#pragma unroll
        for (int chh = 0; chh < 8; chh++) {
            sum2 += red[chh * 33 + t];
            ssq2 += red[chh * 33 + 16 + t];
        }
        float mean2 = sum2 * inv;
        float var2 = fmaxf(ssq2 * inv - mean2 * mean2, 0.f);
        float rs2 = rsqrtf(var2 + 1e-5f);
        float s2v = bn2w[t] * rs2;
        float b2v = bn2b[t] - mean2 * s2v;
        sb[b * 64 + t] = s1v;
        sb[b * 64 + 16 + t] = b1v;
        sb[b * 64 + 32 + t] = s2v;
        sb[b * 64 + 48 + t] = b2v;
    }
}

// ---------------- k_final: persistent pipelined; TPB tiles of 16 points ----------------
__global__ __launch_bounds__(256, 3) void k_final(const float* __restrict__ sup,
                                               const int* __restrict__ nbr,
                                               const float* __restrict__ alpha_,
                                               const float* __restrict__ beta_,
                                               const float* __restrict__ nr_,
                                               const float* __restrict__ fc1,
                                               const float* __restrict__ fc2,
                                               const float* __restrict__ fc3,
                                               const float* __restrict__ sb,
                                               const ushort* __restrict__ cvb,
                                               const ushort* __restrict__ xT,
                                               const float* __restrict__ posT,
                                               float* __restrict__ out) {
    __shared__ __align__(16) ushort ov[16 * OV_STRIDE];
    __shared__ __align__(16) ushort m3l[16 * M3_STRIDE];

    int t = threadIdx.x;
    int b = blockIdx.y;
    int base = blockIdx.x * (16 * TPB);
    int w = t >> 6, l = t & 63;
    int lk = l & 15, kg = l >> 4;
    int ps = t >> 4, ks = t & 15;

    // tile-invariant: per-lane mp-weights + cvb A-frag prefetch + scalars
    float4 w2b0 = *(const float4*)(fc2 + ks * 32 + 16);
    float4 w2b1 = *(const float4*)(fc2 + ks * 32 + 20);
    float4 w2b2 = *(const float4*)(fc2 + ks * 32 + 24);
    float4 w2b3 = *(const float4*)(fc2 + ks * 32 + 28);
    float4 w3b0 = *(const float4*)(fc3 + ks * 32 + 16);
    float4 w3b1 = *(const float4*)(fc3 + ks * 32 + 20);
    float4 w3b2 = *(const float4*)(fc3 + ks * 32 + 24);
    float4 w3b3 = *(const float4*)(fc3 + ks * 32 + 28);
    const ushort* arow = cvb + (size_t)(w * 16 + lk) * 1024;
    ushort8v aupre0 = *(const ushort8v*)(arow + 0 * 32 + kg * 8);
    ushort8v aupre1 = *(const ushort8v*)(arow + 1 * 32 + kg * 8);
    ushort8v aupre2 = *(const ushort8v*)(arow + 2 * 32 + kg * 8);
    ushort8v aupre3 = *(const ushort8v*)(arow + 3 * 32 + kg * 8);

    float alpha = alpha_[0], beta = beta_[0], inr = 1.f / nr_[0];
    const float* sbb = sb + b * 64;
    const f32x4 zz = {0.f, 0.f, 0.f, 0.f};

    // ---- prologue: tile-0 gathers ----
    int idxc = nbr[((size_t)b * MM + base + ps) * KK + ks];
    float4 pf = *(const float4*)(posT + ((size_t)b * NN + idxc) * 4);
    const ushort8v* xr = (const ushort8v*)(xT + ((size_t)b * NN + idxc) * 64);
    ushort8v g0 = xr[0], g1 = xr[1], g2 = xr[2], g3 = xr[3];
    ushort8v g4 = xr[4], g5 = xr[5], g6 = xr[6], g7 = xr[7];
    float sxr = sup[((size_t)b * 3 + 0) * MM + base + ps];
    float syr = sup[((size_t)b * 3 + 1) * MM + base + ps];
    float szr = sup[((size_t)b * 3 + 2) * MM + base + ps];

#pragma unroll
    for (int mt = 0; mt < TPB; ++mt) {
        int m0 = base + mt * 16;
        int nmt = (mt + 1 < TPB) ? (mt + 1) : (TPB - 1);
        // next-tile index load issued early (2-hop dependency covered by this iteration)
        int idxn = nbr[((size_t)b * MM + base + nmt * 16 + ps) * KK + ks];

        // ---- phase 1 (fp32): lane = (point ps, neighbor ks) ----
        {
            float rx = pf.x - sxr, ry = pf.y - syr, rz = pf.z - szr;
            float dd = sqrtf(rx * rx + ry * ry + rz * rz);
            float sr = 1.f / (1.f + expf(alpha * dd - beta));
            float S = gsum16(sr);
            S = S + (S == 0.f ? 1.f : 0.f) + 1e-6f;
            float dwk = sr * (16.f / S);
            float nxv = rx * inr, nyv = ry * inr, nzv = rz * inr;

            float m1v[16], mp1[16];
#pragma unroll
            for (int j = 0; j < 16; j++) {
                float y = fc1[j * 3] * nxv + fc1[j * 3 + 1] * nyv + fc1[j * 3 + 2] * nzv;
                m1v[j] = fmaxf(y * sbb[j] + sbb[16 + j], 0.f);
            }
#pragma unroll
            for (int j = 0; j < 16; j++) mp1[j] = gmax16(m1v[j] * dwk);

            float h2own = w2b0.x * mp1[0] + w2b0.y * mp1[1] + w2b0.z * mp1[2] + w2b0.w * mp1[3]
                        + w2b1.x * mp1[4] + w2b1.y * mp1[5] + w2b1.z * mp1[6] + w2b1.w * mp1[7]
                        + w2b2.x * mp1[8] + w2b2.y * mp1[9] + w2b2.z * mp1[10] + w2b2.w * mp1[11]
                        + w2b3.x * mp1[12] + w2b3.y * mp1[13] + w2b3.z * mp1[14] + w2b3.w * mp1[15];
            int pbase = l & 48;
            float m2v[16], mp2[16];
#pragma unroll
            for (int c = 0; c < 16; c++) {
                float a = 0.f;
#pragma unroll
                for (int q = 0; q < 4; q++) {
                    float4 v = *(const float4*)(fc2 + c * 32 + q * 4);
                    a += v.x * m1v[q * 4] + v.y * m1v[q * 4 + 1] + v.z * m1v[q * 4 + 2] + v.w * m1v[q * 4 + 3];
                }
                a += __shfl(h2own, pbase + c);
                m2v[c] = fmaxf(a * sbb[32 + c] + sbb[48 + c], 0.f);
            }
#pragma unroll
            for (int c = 0; c < 16; c++) mp2[c] = gmax16(m2v[c] * dwk);

            float h3own = w3b0.x * mp2[0] + w3b0.y * mp2[1] + w3b0.z * mp2[2] + w3b0.w * mp2[3]
                        + w3b1.x * mp2[4] + w3b1.y * mp2[5] + w3b1.z * mp2[6] + w3b1.w * mp2[7]
                        + w3b2.x * mp2[8] + w3b2.y * mp2[9] + w3b2.z * mp2[10] + w3b2.w * mp2[11]
                        + w3b3.x * mp2[12] + w3b3.y * mp2[13] + w3b3.z * mp2[14] + w3b3.w * mp2[15];
            ushort* m3p = m3l + ps * M3_STRIDE;
#pragma unroll
            for (int j = 0; j < 16; j++) {
                float a = 0.f;
#pragma unroll
                for (int q = 0; q < 4; q++) {
                    float4 v = *(const float4*)(fc3 + j * 32 + q * 4);
                    a += v.x * m2v[q * 4] + v.y * m2v[q * 4 + 1] + v.z * m2v[q * 4 + 2] + v.w * m2v[q * 4 + 3];
                }
                a += __shfl(h3own, pbase + j);
                m3p[j * 24 + ks] = f2b(fmaxf(a, 0.f) * dwk);
            }
        }

        __syncthreads();   // barrier A: all waves done with previous tile's stage C (ov free)

        // ---- staging: g -> ov[p][c*16 + k] (wave-local) ----
        {
            ushort* ovp = ov + ps * OV_STRIDE;
#define STG(gv, h) _Pragma("unroll") for (int i2 = 0; i2 < 8; i2++) ovp[((h) * 8 + i2) * 16 + ks] = (ushort)gv[i2];
            STG(g0, 0) STG(g1, 1) STG(g2, 2) STG(g3, 3)
            STG(g4, 4) STG(g5, 5) STG(g6, 6) STG(g7, 7)
#undef STG
        }

        // ---- issue next-tile gathers (WAR-safe: after staging consumed g) ----
        pf = *(const float4*)(posT + ((size_t)b * NN + idxn) * 4);
        xr = (const ushort8v*)(xT + ((size_t)b * NN + idxn) * 64);
        g0 = xr[0]; g1 = xr[1]; g2 = xr[2]; g3 = xr[3];
        g4 = xr[4]; g5 = xr[5]; g6 = xr[6]; g7 = xr[7];
        sxr = sup[((size_t)b * 3 + 0) * MM + base + nmt * 16 + ps];
        syr = sup[((size_t)b * 3 + 1) * MM + base + nmt * 16 + ps];
        szr = sup[((size_t)b * 3 + 2) * MM + base + nmt * 16 + ps];

        // ---- stage B (MFMA, wave-local; no barrier needed after staging) ----
#pragma unroll
        for (int pp = 0; pp < 4; pp++) {
            int p = w * 4 + pp;
            bhalf8 afr = {};
            if (kg < 2) afr = __builtin_bit_cast(bhalf8, *(ushort8v*)(m3l + p * M3_STRIDE + lk * 24 + kg * 8));
            ushort* ovb = ov + p * OV_STRIDE;
#pragma unroll
            for (int cb = 0; cb < 4; cb++) {
                bhalf8 bfr = {};
                if (kg < 2) bfr = __builtin_bit_cast(bhalf8, *(ushort8v*)(ovb + (cb * 16 + lk) * 16 + kg * 8));
                f32x4 dF = __builtin_amdgcn_mfma_f32_16x16x32_bf16(afr, bfr, zz, 0, 0, 0);
                ushort4v fw = {f2b(dF[0]), f2b(dF[1]), f2b(dF[2]), f2b(dF[3])};
                *(ushort4v*)(ovb + (cb * 16 + lk) * 16 + kg * 4) = fw;
            }
        }

        __syncthreads();   // barrier B: all feat ready

        // ---- stage C (MFMA): out[o][p] = sum_cj cvb[o][cj] * feat[p][cj]; dual acc ----
        {
            const ushort* brow = ov + lk * OV_STRIDE;
            f32x4 acc0 = zz, acc1 = zz;
#pragma unroll
            for (int kt = 0; kt < 32; kt += 2) {
                bhalf8 au0, au1;
                if (kt == 0) {
                    au0 = __builtin_bit_cast(bhalf8, aupre0);
                    au1 = __builtin_bit_cast(bhalf8, aupre1);
                } else if (kt == 2) {
                    au0 = __builtin_bit_cast(bhalf8, aupre2);
                    au1 = __builtin_bit_cast(bhalf8, aupre3);
                } else {
                    au0 = __builtin_bit_cast(bhalf8, *(const ushort8v*)(arow + kt * 32 + kg * 8));
                    au1 = __builtin_bit_cast(bhalf8, *(const ushort8v*)(arow + (kt + 1) * 32 + kg * 8));
                }
                bhalf8 bu0 = __builtin_bit_cast(bhalf8, *(const ushort8v*)(brow + kt * 32 + kg * 8));
                bhalf8 bu1 = __builtin_bit_cast(bhalf8, *(const ushort8v*)(brow + (kt + 1) * 32 + kg * 8));
                acc0 = __builtin_amdgcn_mfma_f32_16x16x32_bf16(au0, bu0, acc0, 0, 0, 0);
                acc1 = __builtin_amdgcn_mfma_f32_16x16x32_bf16(au1, bu1, acc1, 0, 0, 0);
            }
#pragma unroll
            for (int r = 0; r < 4; r++) {
                int o = w * 16 + kg * 4 + r;
                out[((size_t)(b * 64 + o)) * MM + m0 + lk] = acc0[r] + acc1[r];
            }
        }
    }
}

extern "C" void kernel_launch(void* const* d_in, const int* in_sizes, int n_in,
                              void* d_out, int out_size, void* d_ws, size_t ws_size,
                              hipStream_t stream) {
    const float* x    = (const float*)d_in[0];
    const float* pos  = (const float*)d_in[1];
    const float* sup  = (const float*)d_in[2];
    const int*   nbr  = (const int*)d_in[3];
    const float* alp  = (const float*)d_in[4];
    const float* bet  = (const float*)d_in[5];
    const float* nr   = (const float*)d_in[6];
    const float* fc1  = (const float*)d_in[7];
    const float* fc2  = (const float*)d_in[8];
    const float* fc3  = (const float*)d_in[9];
    const float* bn1w = (const float*)d_in[10];
    const float* bn1b = (const float*)d_in[11];
    const float* bn2w = (const float*)d_in[12];
    const float* bn2b = (const float*)d_in[13];
    const float* cv   = (const float*)d_in[14];
    float* out = (float*)d_out;
    ushort* cvb  = (ushort*)((char*)d_ws + WS_CVB_BYTE);
    ushort* xT   = (ushort*)((char*)d_ws + WS_XT_BYTE);
    float*  posT = (float*)((char*)d_ws + WS_PT_BYTE);
    float*  momp = (float*)((char*)d_ws + WS_MOMP_BYTE);
    float*  p2   = (float*)((char*)d_ws + WS_P2_BYTE);
    float*  sb   = (float*)((char*)d_ws + WS_SB_BYTE);

    k_pre<<<704, 256, 0, stream>>>(x, pos, sup, nbr, cv, momp, cvb, xT, posT);
    k_stats2<<<dim3(128, BB), 256, 0, stream>>>(sup, nbr, alp, bet, nr, fc1, fc2,
                                                bn1w, bn1b, posT, momp, p2);
    k_fin<<<BB, 256, 0, stream>>>(momp, p2, fc1, bn1w, bn1b, bn2w, bn2b, nr, sb);
    k_final<<<dim3(MM / (16 * TPB), BB), 256, 0, stream>>>(sup, nbr, alp, bet, nr,
                                                           fc1, fc2, fc3, sb, cvb,
                                                           xT, posT, out);
}

// Round 14
// 91.695 us; speedup vs baseline: 1.1050x; 1.0559x over previous
//
#include <hip/hip_runtime.h>
#include <math.h>

#define BB 4
#define NN 8192
#define MM 8192
#define KK 16

// byte offsets for scratch regions
#define WS_CVB_BYTE  2048                        // 64*1024 ush = 131072 B
#define WS_XT_BYTE   (WS_CVB_BYTE + 131072)      // 4*8192*64 ush = 4194304 B
#define WS_PT_BYTE   (WS_XT_BYTE + 4194304)      // 4*8192*4 f32 = 524288 B
#define WS_MOMP_BYTE (WS_PT_BYTE + 524288)       // 128 blk * 12 f32 = 6144 B
#define WS_P2_BYTE   (WS_MOMP_BYTE + 6144)       // 512 blk * 32 f32 = 65536 B
#define WS_SB_BYTE   (WS_P2_BYTE + 65536)        // 4 * 64 f32 = 1024 B

#define OV_STRIDE 1040   // R9-proven
#define M3_STRIDE 408    // 204 dw = 12 mod 32: wave's 4 points hit distinct bank groups

typedef __bf16 bhalf;
typedef bhalf bhalf8 __attribute__((ext_vector_type(8)));
typedef float f32x4 __attribute__((ext_vector_type(4)));
typedef ushort ushort8v __attribute__((ext_vector_type(8)));
typedef ushort ushort4v __attribute__((ext_vector_type(4)));

static __device__ __forceinline__ ushort f2b(float f) {
    return __builtin_bit_cast(ushort, (__bf16)f);
}

// ---- DPP row reductions (16-lane rows), VALU-only: row_ror 1,2,4,8 ----
template <int CTRL>
__device__ __forceinline__ float dpp_rot(float v) {
    int r = __builtin_amdgcn_update_dpp(0, __builtin_bit_cast(int, v), CTRL, 0xF, 0xF, true);
    return __builtin_bit_cast(float, r);
}
__device__ __forceinline__ float gmax16(float v) {
    v = fmaxf(v, dpp_rot<0x121>(v));
    v = fmaxf(v, dpp_rot<0x122>(v));
    v = fmaxf(v, dpp_rot<0x124>(v));
    v = fmaxf(v, dpp_rot<0x128>(v));
    return v;
}
__device__ __forceinline__ float gsum16(float v) {
    v += dpp_rot<0x121>(v);
    v += dpp_rot<0x122>(v);
    v += dpp_rot<0x124>(v);
    v += dpp_rot<0x128>(v);
    return v;
}

// ---------------- k_pre: xT transpose+bf16, posT, cvb, moment partials ----------------
__global__ __launch_bounds__(256) void k_pre(const float* __restrict__ x,
                                             const float* __restrict__ pos,
                                             const float* __restrict__ sup,
                                             const int* __restrict__ nbr,
                                             const float* __restrict__ cv,
                                             float* __restrict__ momp,
                                             ushort* __restrict__ cvb,
                                             ushort* __restrict__ xT,
                                             float* __restrict__ posT) {
    int bid = blockIdx.x, t = threadIdx.x;
    if (bid < 512) {
        int b = bid >> 7, n0 = (bid & 127) * 64;
        __shared__ ushort tile[64 * 66];
        const float* xb = x + (size_t)b * 64 * NN;
#pragma unroll
        for (int i = 0; i < 16; i++) {
            int c = i * 4 + (t >> 6), n = t & 63;
            tile[c * 66 + n] = f2b(xb[(size_t)c * NN + n0 + n]);
        }
        __syncthreads();
#pragma unroll
        for (int i = 0; i < 16; i++) {
            int n = i * 4 + (t >> 6), c = t & 63;
            xT[((size_t)b * NN + n0 + n) * 64 + c] = tile[c * 66 + n];
        }
        int nl = t >> 2, d = t & 3;
        float v = (d < 3) ? pos[((size_t)b * 3 + d) * NN + n0 + nl] : 0.f;
        posT[((size_t)b * NN + n0 + nl) * 4 + d] = v;
    } else if (bid < 576) {
        int e = (bid - 512) * 1024 + t * 4;
        float4 cvv = *(const float4*)(cv + e);
        ushort4v o = {f2b(cvv.x), f2b(cvv.y), f2b(cvv.z), f2b(cvv.w)};
        *(ushort4v*)(cvb + e) = o;
    } else {
        __shared__ float redm[36];
        int rem = bid - 576;
        int b = rem & 3, m = (rem >> 2) * 256 + t;
        const float* posb = pos + (size_t)b * 3 * NN;
        float sx = sup[((size_t)b * 3 + 0) * MM + m];
        float sy = sup[((size_t)b * 3 + 1) * MM + m];
        float sz = sup[((size_t)b * 3 + 2) * MM + m];
        const int* nb = nbr + ((size_t)b * MM + m) * KK;
        float s[9] = {0, 0, 0, 0, 0, 0, 0, 0, 0};
#pragma unroll
        for (int k = 0; k < KK; k++) {
            int id = nb[k];
            float px = posb[id] - sx, py = posb[NN + id] - sy, pz = posb[2 * NN + id] - sz;
            s[0] += px; s[1] += py; s[2] += pz;
            s[3] += px * px; s[4] += py * py; s[5] += pz * pz;
            s[6] += px * py; s[7] += px * pz; s[8] += py * pz;
        }
#pragma unroll
        for (int i = 0; i < 9; i++) {
            float v = s[i];
#pragma unroll
            for (int off = 32; off >= 1; off >>= 1) v += __shfl_down(v, off);
            if ((t & 63) == 0) redm[(t >> 6) * 9 + i] = v;
        }
        __syncthreads();
        if (t < 9) momp[rem * 12 + t] = redm[t] + redm[9 + t] + redm[18 + t] + redm[27 + t];
    }
}

// ---------------- k_stats2: per-(b,c) stats partials, zero atomics, scalar weights ----
__global__ __launch_bounds__(256) void k_stats2(const float* __restrict__ sup,
                                                const int* __restrict__ nbr,
                                                const float* __restrict__ alpha_,
                                                const float* __restrict__ beta_,
                                                const float* __restrict__ nr_,
                                                const float* __restrict__ fc1,
                                                const float* __restrict__ fc2,
                                                const float* __restrict__ bn1w,
                                                const float* __restrict__ bn1b,
                                                const float* __restrict__ posT,
                                                const float* __restrict__ momp,
                                                float* __restrict__ p2) {
    __shared__ float sc1[16], bi1[16], momr[9], red[4 * 33];
    int t = threadIdx.x, b = blockIdx.y;
    if (t < 9) {
        float s = 0.f;
#pragma unroll
        for (int g = 0; g < 32; g++) s += momp[(4 * g + b) * 12 + t];
        momr[t] = s;
    }
    __syncthreads();
    if (t < 16) {
        float inv = 1.f / (float)(MM * KK);
        float inr = 1.f / nr_[0];
        float mux = momr[0] * inv * inr, muy = momr[1] * inv * inr, muz = momr[2] * inv * inr;
        float i2 = inv * inr * inr;
        float w0 = fc1[t * 3], w1v = fc1[t * 3 + 1], w2v = fc1[t * 3 + 2];
        float mean = w0 * mux + w1v * muy + w2v * muz;
        float ey2 = w0 * w0 * momr[3] * i2 + w1v * w1v * momr[4] * i2 + w2v * w2v * momr[5] * i2 +
                    2.f * (w0 * w1v * momr[6] * i2 + w0 * w2v * momr[7] * i2 + w1v * w2v * momr[8] * i2);
        float var = fmaxf(ey2 - mean * mean, 0.f);
        float rs = rsqrtf(var + 1e-5f);
        sc1[t] = bn1w[t] * rs;
        bi1[t] = bn1b[t] - mean * sc1[t];
    }
    __syncthreads();
    int mi = t >> 2, kq = t & 3;
    int m = blockIdx.x * 64 + mi;
    float alpha = alpha_[0], beta = beta_[0], inr = 1.f / nr_[0];
    float sx = sup[((size_t)b * 3 + 0) * MM + m];
    float sy = sup[((size_t)b * 3 + 1) * MM + m];
    float sz = sup[((size_t)b * 3 + 2) * MM + m];
    const int* nb = nbr + ((size_t)b * MM + m) * KK + kq * 4;

    float q1m[16], G1[16], G2[16];
#pragma unroll
    for (int j = 0; j < 16; j++) { q1m[j] = 0.f; G1[j] = 0.f; G2[j] = 0.f; }
    float S = 0.f;
#pragma unroll
    for (int kk = 0; kk < 4; kk++) {
        int id = nb[kk];
        float4 pv = *(const float4*)(posT + ((size_t)b * NN + id) * 4);
        float rx = pv.x - sx, ry = pv.y - sy, rz = pv.z - sz;
        float dd = sqrtf(rx * rx + ry * ry + rz * rz);
        float srk = 1.f / (1.f + expf(alpha * dd - beta));
        S += srk;
        float nxv = rx * inr, nyv = ry * inr, nzv = rz * inr;
        float m1c[16];
#pragma unroll
        for (int j = 0; j < 16; j++) {
            float y = fc1[j * 3] * nxv + fc1[j * 3 + 1] * nyv + fc1[j * 3 + 2] * nzv;
            m1c[j] = fmaxf(y * sc1[j] + bi1[j], 0.f);
            q1m[j] = fmaxf(q1m[j], m1c[j] * srk);
        }
#pragma unroll
        for (int c = 0; c < 16; c++) {
            float g = 0.f;
#pragma unroll
            for (int q = 0; q < 4; q++) {
                float4 v = *(const float4*)(fc2 + c * 32 + q * 4);
                g += v.x * m1c[q * 4] + v.y * m1c[q * 4 + 1] +
                     v.z * m1c[q * 4 + 2] + v.w * m1c[q * 4 + 3];
            }
            G1[c] += g; G2[c] += g * g;
        }
    }
    S += __shfl_xor(S, 1); S += __shfl_xor(S, 2);
#pragma unroll
    for (int j = 0; j < 16; j++) {
        q1m[j] = fmaxf(q1m[j], __shfl_xor(q1m[j], 1));
        q1m[j] = fmaxf(q1m[j], __shfl_xor(q1m[j], 2));
    }
    S = S + (S == 0.f ? 1.f : 0.f) + 1e-6f;
    float fac = 16.f / S;
#pragma unroll
    for (int c = 0; c < 16; c++) {
        float h2 = 0.f;
#pragma unroll
        for (int q = 0; q < 4; q++) {
            float4 v = *(const float4*)(fc2 + c * 32 + 16 + q * 4);
            h2 += v.x * q1m[q * 4] + v.y * q1m[q * 4 + 1] +
                  v.z * q1m[q * 4 + 2] + v.w * q1m[q * 4 + 3];
        }
        h2 *= fac;
        float s2p = G1[c] + 4.f * h2;
        float q2p = G2[c] + 2.f * h2 * G1[c] + 4.f * h2 * h2;
#pragma unroll
        for (int off = 32; off >= 1; off >>= 1) {
            s2p += __shfl_down(s2p, off);
            q2p += __shfl_down(q2p, off);
        }
        if ((t & 63) == 0) {
            red[(t >> 6) * 33 + c] = s2p;
            red[(t >> 6) * 33 + 16 + c] = q2p;
        }
    }
    __syncthreads();
    if (t < 32)
        p2[((size_t)b * 128 + blockIdx.x) * 32 + t] =
            red[t] + red[33 + t] + red[66 + t] + red[99 + t];
}

// ---------------- k_fin: final reduce momp/p2 -> s1,b1,s2,b2 per batch ----------------
__global__ __launch_bounds__(256) void k_fin(const float* __restrict__ momp,
                                             const float* __restrict__ p2,
                                             const float* __restrict__ fc1,
                                             const float* __restrict__ bn1w,
                                             const float* __restrict__ bn1b,
                                             const float* __restrict__ bn2w,
                                             const float* __restrict__ bn2b,
                                             const float* __restrict__ nr_,
                                             float* __restrict__ sb) {
    __shared__ float red[8 * 33], momr[9];
    int b = blockIdx.x, t = threadIdx.x;
    int c = t & 31, ch = t >> 5;
    float s = 0.f;
#pragma unroll
    for (int g = 0; g < 16; g++) s += p2[((size_t)b * 128 + ch * 16 + g) * 32 + c];
    red[ch * 33 + c] = s;
    if (t < 9) {
        float v = 0.f;
#pragma unroll
        for (int g = 0; g < 32; g++) v += momp[(4 * g + b) * 12 + t];
        momr[t] = v;
    }
    __syncthreads();
    if (t < 16) {
        float inv = 1.f / (float)(MM * KK);
        float inr = 1.f / nr_[0];
        float mux = momr[0] * inv * inr, muy = momr[1] * inv * inr, muz = momr[2] * inv * inr;
        float i2 = inv * inr * inr;
        float w0 = fc1[t * 3], wa = fc1[t * 3 + 1], wb = fc1[t * 3 + 2];
        float mean = w0 * mux + wa * muy + wb * muz;
        float ey2 = w0 * w0 * momr[3] * i2 + wa * wa * momr[4] * i2 + wb * wb * momr[5] * i2 +
                    2.f * (w0 * wa * momr[6] * i2 + w0 * wb * momr[7] * i2 + wa * wb * momr[8] * i2);
        float var = fmaxf(ey2 - mean * mean, 0.f);
        float rs = rsqrtf(var + 1e-5f);
        float s1v = bn1w[t] * rs;
        float b1v = bn1b[t] - mean * s1v;
        float sum2 = 0.f, ssq2 = 0.f;
#pragma unroll
        for (int chh = 0; chh < 8; chh++) {
            sum2 += red[chh * 33 + t];
            ssq2 += red[chh * 33 + 16 + t];
        }
        float mean2 = sum2 * inv;
        float var2 = fmaxf(ssq2 * inv - mean2 * mean2, 0.f);
        float rs2 = rsqrtf(var2 + 1e-5f);
        float s2v = bn2w[t] * rs2;
        float b2v = bn2b[t] - mean2 * s2v;
        sb[b * 64 + t] = s1v;
        sb[b * 64 + 16 + t] = b1v;
        sb[b * 64 + 32 + t] = s2v;
        sb[b * 64 + 48 + t] = b2v;
    }
}

// ---------------- k_final: R9 structure + M3 stride fix + setprio + 8-frag prefetch ----
__global__ __launch_bounds__(256, 3) void k_final(const float* __restrict__ sup,
                                               const int* __restrict__ nbr,
                                               const float* __restrict__ alpha_,
                                               const float* __restrict__ beta_,
                                               const float* __restrict__ nr_,
                                               const float* __restrict__ fc1,
                                               const float* __restrict__ fc2,
                                               const float* __restrict__ fc3,
                                               const float* __restrict__ sb,
                                               const ushort* __restrict__ cvb,
                                               const ushort* __restrict__ xT,
                                               const float* __restrict__ posT,
                                               float* __restrict__ out) {
    __shared__ __align__(16) ushort ov[16 * OV_STRIDE]; // per point: xg[c][k], feat overlay
    __shared__ __align__(16) ushort m3l[16 * M3_STRIDE];// [p][j*24 + k]

    int t = threadIdx.x;
    int b = blockIdx.y;
    int m0 = blockIdx.x * 16;
    int w = t >> 6, l = t & 63;
    int lk = l & 15, kg = l >> 4;
    int ps = t >> 4, ks = t & 15;

    // ---- staging loads issued early ----
    int idxt = nbr[((size_t)b * MM + m0 + ps) * KK + ks];
    float4 pf = *(const float4*)(posT + ((size_t)b * NN + idxt) * 4);
    const ushort8v* xrow = (const ushort8v*)(xT + ((size_t)b * NN + idxt) * 64);
    ushort8v g0 = xrow[0], g1 = xrow[1], g2 = xrow[2], g3 = xrow[3];
    ushort8v g4 = xrow[4], g5 = xrow[5], g6 = xrow[6], g7 = xrow[7];
    float4 w2b0 = *(const float4*)(fc2 + ks * 32 + 16);
    float4 w2b1 = *(const float4*)(fc2 + ks * 32 + 20);
    float4 w2b2 = *(const float4*)(fc2 + ks * 32 + 24);
    float4 w2b3 = *(const float4*)(fc2 + ks * 32 + 28);
    float4 w3b0 = *(const float4*)(fc3 + ks * 32 + 16);
    float4 w3b1 = *(const float4*)(fc3 + ks * 32 + 20);
    float4 w3b2 = *(const float4*)(fc3 + ks * 32 + 24);
    float4 w3b3 = *(const float4*)(fc3 + ks * 32 + 28);

    float alpha = alpha_[0], beta = beta_[0], inr = 1.f / nr_[0];
    const float* sbb = sb + b * 64;

    // ---- phase 1 (fp32): lane = (point ps, neighbor ks) ----
    {
        int mm = m0 + ps;
        float rx = pf.x - sup[((size_t)b * 3 + 0) * MM + mm];
        float ry = pf.y - sup[((size_t)b * 3 + 1) * MM + mm];
        float rz = pf.z - sup[((size_t)b * 3 + 2) * MM + mm];
        float dd = sqrtf(rx * rx + ry * ry + rz * rz);
        float sr = 1.f / (1.f + expf(alpha * dd - beta));
        float S = gsum16(sr);
        S = S + (S == 0.f ? 1.f : 0.f) + 1e-6f;
        float dwk = sr * (16.f / S);
        float nxv = rx * inr, nyv = ry * inr, nzv = rz * inr;

        float m1v[16], mp1[16];
#pragma unroll
        for (int j = 0; j < 16; j++) {
            float y = fc1[j * 3] * nxv + fc1[j * 3 + 1] * nyv + fc1[j * 3 + 2] * nzv;
            m1v[j] = fmaxf(y * sbb[j] + sbb[16 + j], 0.f);
        }
#pragma unroll
        for (int j = 0; j < 16; j++) mp1[j] = gmax16(m1v[j] * dwk);

        float h2own = w2b0.x * mp1[0] + w2b0.y * mp1[1] + w2b0.z * mp1[2] + w2b0.w * mp1[3]
                    + w2b1.x * mp1[4] + w2b1.y * mp1[5] + w2b1.z * mp1[6] + w2b1.w * mp1[7]
                    + w2b2.x * mp1[8] + w2b2.y * mp1[9] + w2b2.z * mp1[10] + w2b2.w * mp1[11]
                    + w2b3.x * mp1[12] + w2b3.y * mp1[13] + w2b3.z * mp1[14] + w2b3.w * mp1[15];
        int pbase = l & 48;
        float m2v[16], mp2[16];
#pragma unroll
        for (int c = 0; c < 16; c++) {
            float a = 0.f;
#pragma unroll
            for (int q = 0; q < 4; q++) {
                float4 v = *(const float4*)(fc2 + c * 32 + q * 4);
                a += v.x * m1v[q * 4] + v.y * m1v[q * 4 + 1] + v.z * m1v[q * 4 + 2] + v.w * m1v[q * 4 + 3];
            }
            a += __shfl(h2own, pbase + c);
            m2v[c] = fmaxf(a * sbb[32 + c] + sbb[48 + c], 0.f);
        }
#pragma unroll
        for (int c = 0; c < 16; c++) mp2[c] = gmax16(m2v[c] * dwk);

        float h3own = w3b0.x * mp2[0] + w3b0.y * mp2[1] + w3b0.z * mp2[2] + w3b0.w * mp2[3]
                    + w3b1.x * mp2[4] + w3b1.y * mp2[5] + w3b1.z * mp2[6] + w3b1.w * mp2[7]
                    + w3b2.x * mp2[8] + w3b2.y * mp2[9] + w3b2.z * mp2[10] + w3b2.w * mp2[11]
                    + w3b3.x * mp2[12] + w3b3.y * mp2[13] + w3b3.z * mp2[14] + w3b3.w * mp2[15];
        ushort* m3p = m3l + ps * M3_STRIDE;
#pragma unroll
        for (int j = 0; j < 16; j++) {
            float a = 0.f;
#pragma unroll
            for (int q = 0; q < 4; q++) {
                float4 v = *(const float4*)(fc3 + j * 32 + q * 4);
                a += v.x * m2v[q * 4] + v.y * m2v[q * 4 + 1] + v.z * m2v[q * 4 + 2] + v.w * m2v[q * 4 + 3];
            }
            a += __shfl(h3own, pbase + j);
            m3p[j * 24 + ks] = f2b(fmaxf(a, 0.f) * dwk);
        }
    }

    // ---- write staged xg rows: ov[p][c*16 + k]  (wave-local) ----
    {
        ushort* ovp = ov + ps * OV_STRIDE;
#define STG(gv, h) _Pragma("unroll") for (int i2 = 0; i2 < 8; i2++) ovp[((h) * 8 + i2) * 16 + ks] = (ushort)gv[i2];
        STG(g0, 0) STG(g1, 1) STG(g2, 2) STG(g3, 3)
        STG(g4, 4) STG(g5, 5) STG(g6, 6) STG(g7, 7)
#undef STG
    }
    // NO barrier: stage B touches only this wave's points

    const f32x4 zz = {0.f, 0.f, 0.f, 0.f};

    // ---- stage B (MFMA, wave-local) ----
    __builtin_amdgcn_s_setprio(1);
#pragma unroll
    for (int pp = 0; pp < 4; pp++) {
        int p = w * 4 + pp;
        bhalf8 afr = {};
        if (kg < 2) afr = __builtin_bit_cast(bhalf8, *(ushort8v*)(m3l + p * M3_STRIDE + lk * 24 + kg * 8));
        ushort* ovb = ov + p * OV_STRIDE;
#pragma unroll
        for (int cb = 0; cb < 4; cb++) {
            bhalf8 bfr = {};
            if (kg < 2) bfr = __builtin_bit_cast(bhalf8, *(ushort8v*)(ovb + (cb * 16 + lk) * 16 + kg * 8));
            f32x4 dF = __builtin_amdgcn_mfma_f32_16x16x32_bf16(afr, bfr, zz, 0, 0, 0);
            ushort4v fw = {f2b(dF[0]), f2b(dF[1]), f2b(dF[2]), f2b(dF[3])};
            *(ushort4v*)(ovb + (cb * 16 + lk) * 16 + kg * 4) = fw;
        }
    }
    __builtin_amdgcn_s_setprio(0);

    // ---- prefetch first 8 stage-C A-fragments (tile-invariant, global) ----
    const ushort* arow = cvb + (size_t)(w * 16 + lk) * 1024;
    ushort8v aupre[8];
#pragma unroll
    for (int q = 0; q < 8; q++)
        aupre[q] = *(const ushort8v*)(arow + q * 32 + kg * 8);

    __syncthreads();   // the ONE barrier: stage C reads all points' feat

    // ---- stage C (MFMA): out[o][p] = sum_cj cvb[o][cj] * feat[p][cj]; dual acc ----
    {
        const ushort* brow = ov + lk * OV_STRIDE;
        f32x4 acc0 = zz, acc1 = zz;
        __builtin_amdgcn_s_setprio(1);
#pragma unroll
        for (int kt = 0; kt < 32; kt += 2) {
            bhalf8 au0, au1;
            if (kt < 8) {
                au0 = __builtin_bit_cast(bhalf8, aupre[kt]);
                au1 = __builtin_bit_cast(bhalf8, aupre[kt + 1]);
            } else {
                au0 = __builtin_bit_cast(bhalf8, *(const ushort8v*)(arow + kt * 32 + kg * 8));
                au1 = __builtin_bit_cast(bhalf8, *(const ushort8v*)(arow + (kt + 1) * 32 + kg * 8));
            }
            bhalf8 bu0 = __builtin_bit_cast(bhalf8, *(const ushort8v*)(brow + kt * 32 + kg * 8));
            bhalf8 bu1 = __builtin_bit_cast(bhalf8, *(const ushort8v*)(brow + (kt + 1) * 32 + kg * 8));
            acc0 = __builtin_amdgcn_mfma_f32_16x16x32_bf16(au0, bu0, acc0, 0, 0, 0);
            acc1 = __builtin_amdgcn_mfma_f32_16x16x32_bf16(au1, bu1, acc1, 0, 0, 0);
        }
        __builtin_amdgcn_s_setprio(0);
#pragma unroll
        for (int r = 0; r < 4; r++) {
            int o = w * 16 + kg * 4 + r;
            out[((size_t)(b * 64 + o)) * MM + m0 + lk] = acc0[r] + acc1[r];
        }
    }
}

extern "C" void kernel_launch(void* const* d_in, const int* in_sizes, int n_in,
                              void* d_out, int out_size, void* d_ws, size_t ws_size,
                              hipStream_t stream) {
    const float* x    = (const float*)d_in[0];
    const float* pos  = (const float*)d_in[1];
    const float* sup  = (const float*)d_in[2];
    const int*   nbr  = (const int*)d_in[3];
    const float* alp  = (const float*)d_in[4];
    const float* bet  = (const float*)d_in[5];
    const float* nr   = (const float*)d_in[6];
    const float* fc1  = (const float*)d_in[7];
    const float* fc2  = (const float*)d_in[8];
    const float* fc3  = (const float*)d_in[9];
    const float* bn1w = (const float*)d_in[10];
    const float* bn1b = (const float*)d_in[11];
    const float* bn2w = (const float*)d_in[12];
    const float* bn2b = (const float*)d_in[13];
    const float* cv   = (const float*)d_in[14];
    float* out = (float*)d_out;
    ushort* cvb  = (ushort*)((char*)d_ws + WS_CVB_BYTE);
    ushort* xT   = (ushort*)((char*)d_ws + WS_XT_BYTE);
    float*  posT = (float*)((char*)d_ws + WS_PT_BYTE);
    float*  momp = (float*)((char*)d_ws + WS_MOMP_BYTE);
    float*  p2   = (float*)((char*)d_ws + WS_P2_BYTE);
    float*  sb   = (float*)((char*)d_ws + WS_SB_BYTE);

    k_pre<<<704, 256, 0, stream>>>(x, pos, sup, nbr, cv, momp, cvb, xT, posT);
    k_stats2<<<dim3(128, BB), 256, 0, stream>>>(sup, nbr, alp, bet, nr, fc1, fc2,
                                                bn1w, bn1b, posT, momp, p2);
    k_fin<<<BB, 256, 0, stream>>>(momp, p2, fc1, bn1w, bn1b, bn2w, bn2b, nr, sb);
    k_final<<<dim3(512, BB), 256, 0, stream>>>(sup, nbr, alp, bet, nr, fc1, fc2, fc3,
                                               sb, cvb, xT, posT, out);
}

// Round 15
// 87.730 us; speedup vs baseline: 1.1549x; 1.0452x over previous
//
#include <hip/hip_runtime.h>
#include <math.h>

#define BB 4
#define NN 8192
#define MM 8192
#define KK 16

// byte offsets for scratch regions
#define WS_CVB_BYTE  2048                        // 64*1024 ush = 131072 B
#define WS_XT_BYTE   (WS_CVB_BYTE + 131072)      // 4*8192*64 ush = 4194304 B
#define WS_PT_BYTE   (WS_XT_BYTE + 4194304)      // 4*8192*4 f32 = 524288 B
#define WS_MOMP_BYTE (WS_PT_BYTE + 524288)       // 128 blk * 12 f32 = 6144 B
#define WS_P2_BYTE   (WS_MOMP_BYTE + 6144)       // 512 blk * 32 f32 = 65536 B
#define WS_SB_BYTE   (WS_P2_BYTE + 65536)        // 4 * 64 f32 = 1024 B

#define OV_STRIDE 1040   // R9-proven
#define M3_STRIDE 408    // 204 dw = 12 mod 32 (R14: conflicts 1.9M -> 1.64M)

typedef __bf16 bhalf;
typedef bhalf bhalf8 __attribute__((ext_vector_type(8)));
typedef float f32x4 __attribute__((ext_vector_type(4)));
typedef ushort ushort8v __attribute__((ext_vector_type(8)));
typedef ushort ushort4v __attribute__((ext_vector_type(4)));

static __device__ __forceinline__ ushort f2b(float f) {
    return __builtin_bit_cast(ushort, (__bf16)f);
}

// ---- DPP row reductions (16-lane rows), VALU-only: row_ror 1,2,4,8 ----
template <int CTRL>
__device__ __forceinline__ float dpp_rot(float v) {
    int r = __builtin_amdgcn_update_dpp(0, __builtin_bit_cast(int, v), CTRL, 0xF, 0xF, true);
    return __builtin_bit_cast(float, r);
}
__device__ __forceinline__ float gmax16(float v) {
    v = fmaxf(v, dpp_rot<0x121>(v));
    v = fmaxf(v, dpp_rot<0x122>(v));
    v = fmaxf(v, dpp_rot<0x124>(v));
    v = fmaxf(v, dpp_rot<0x128>(v));
    return v;
}
__device__ __forceinline__ float gsum16(float v) {
    v += dpp_rot<0x121>(v);
    v += dpp_rot<0x122>(v);
    v += dpp_rot<0x124>(v);
    v += dpp_rot<0x128>(v);
    return v;
}

// ---------------- k_pre: xT transpose+bf16, posT, cvb, moment partials ----------------
__global__ __launch_bounds__(256) void k_pre(const float* __restrict__ x,
                                             const float* __restrict__ pos,
                                             const float* __restrict__ sup,
                                             const int* __restrict__ nbr,
                                             const float* __restrict__ cv,
                                             float* __restrict__ momp,
                                             ushort* __restrict__ cvb,
                                             ushort* __restrict__ xT,
                                             float* __restrict__ posT) {
    int bid = blockIdx.x, t = threadIdx.x;
    if (bid < 512) {
        int b = bid >> 7, n0 = (bid & 127) * 64;
        __shared__ ushort tile[64 * 66];
        const float* xb = x + (size_t)b * 64 * NN;
#pragma unroll
        for (int i = 0; i < 16; i++) {
            int c = i * 4 + (t >> 6), n = t & 63;
            tile[c * 66 + n] = f2b(xb[(size_t)c * NN + n0 + n]);
        }
        __syncthreads();
#pragma unroll
        for (int i = 0; i < 16; i++) {
            int n = i * 4 + (t >> 6), c = t & 63;
            xT[((size_t)b * NN + n0 + n) * 64 + c] = tile[c * 66 + n];
        }
        int nl = t >> 2, d = t & 3;
        float v = (d < 3) ? pos[((size_t)b * 3 + d) * NN + n0 + nl] : 0.f;
        posT[((size_t)b * NN + n0 + nl) * 4 + d] = v;
    } else if (bid < 576) {
        int e = (bid - 512) * 1024 + t * 4;
        float4 cvv = *(const float4*)(cv + e);
        ushort4v o = {f2b(cvv.x), f2b(cvv.y), f2b(cvv.z), f2b(cvv.w)};
        *(ushort4v*)(cvb + e) = o;
    } else {
        __shared__ float redm[36];
        int rem = bid - 576;
        int b = rem & 3, m = (rem >> 2) * 256 + t;
        const float* posb = pos + (size_t)b * 3 * NN;
        float sx = sup[((size_t)b * 3 + 0) * MM + m];
        float sy = sup[((size_t)b * 3 + 1) * MM + m];
        float sz = sup[((size_t)b * 3 + 2) * MM + m];
        const int* nb = nbr + ((size_t)b * MM + m) * KK;
        float s[9] = {0, 0, 0, 0, 0, 0, 0, 0, 0};
#pragma unroll
        for (int k = 0; k < KK; k++) {
            int id = nb[k];
            float px = posb[id] - sx, py = posb[NN + id] - sy, pz = posb[2 * NN + id] - sz;
            s[0] += px; s[1] += py; s[2] += pz;
            s[3] += px * px; s[4] += py * py; s[5] += pz * pz;
            s[6] += px * py; s[7] += px * pz; s[8] += py * pz;
        }
#pragma unroll
        for (int i = 0; i < 9; i++) {
            float v = s[i];
#pragma unroll
            for (int off = 32; off >= 1; off >>= 1) v += __shfl_down(v, off);
            if ((t & 63) == 0) redm[(t >> 6) * 9 + i] = v;
        }
        __syncthreads();
        if (t < 9) momp[rem * 12 + t] = redm[t] + redm[9 + t] + redm[18 + t] + redm[27 + t];
    }
}

// ---------------- k_stats2: per-(b,c) stats partials, zero atomics, scalar weights ----
__global__ __launch_bounds__(256) void k_stats2(const float* __restrict__ sup,
                                                const int* __restrict__ nbr,
                                                const float* __restrict__ alpha_,
                                                const float* __restrict__ beta_,
                                                const float* __restrict__ nr_,
                                                const float* __restrict__ fc1,
                                                const float* __restrict__ fc2,
                                                const float* __restrict__ bn1w,
                                                const float* __restrict__ bn1b,
                                                const float* __restrict__ posT,
                                                const float* __restrict__ momp,
                                                float* __restrict__ p2) {
    __shared__ float sc1[16], bi1[16], momr[9], red[4 * 33];
    int t = threadIdx.x, b = blockIdx.y;
    if (t < 9) {
        float s = 0.f;
#pragma unroll
        for (int g = 0; g < 32; g++) s += momp[(4 * g + b) * 12 + t];
        momr[t] = s;
    }
    __syncthreads();
    if (t < 16) {
        float inv = 1.f / (float)(MM * KK);
        float inr = 1.f / nr_[0];
        float mux = momr[0] * inv * inr, muy = momr[1] * inv * inr, muz = momr[2] * inv * inr;
        float i2 = inv * inr * inr;
        float w0 = fc1[t * 3], w1v = fc1[t * 3 + 1], w2v = fc1[t * 3 + 2];
        float mean = w0 * mux + w1v * muy + w2v * muz;
        float ey2 = w0 * w0 * momr[3] * i2 + w1v * w1v * momr[4] * i2 + w2v * w2v * momr[5] * i2 +
                    2.f * (w0 * w1v * momr[6] * i2 + w0 * w2v * momr[7] * i2 + w1v * w2v * momr[8] * i2);
        float var = fmaxf(ey2 - mean * mean, 0.f);
        float rs = rsqrtf(var + 1e-5f);
        sc1[t] = bn1w[t] * rs;
        bi1[t] = bn1b[t] - mean * sc1[t];
    }
    __syncthreads();
    int mi = t >> 2, kq = t & 3;
    int m = blockIdx.x * 64 + mi;
    float alpha = alpha_[0], beta = beta_[0], inr = 1.f / nr_[0];
    float sx = sup[((size_t)b * 3 + 0) * MM + m];
    float sy = sup[((size_t)b * 3 + 1) * MM + m];
    float sz = sup[((size_t)b * 3 + 2) * MM + m];
    const int* nb = nbr + ((size_t)b * MM + m) * KK + kq * 4;

    float q1m[16], G1[16], G2[16];
#pragma unroll
    for (int j = 0; j < 16; j++) { q1m[j] = 0.f; G1[j] = 0.f; G2[j] = 0.f; }
    float S = 0.f;
#pragma unroll
    for (int kk = 0; kk < 4; kk++) {
        int id = nb[kk];
        float4 pv = *(const float4*)(posT + ((size_t)b * NN + id) * 4);
        float rx = pv.x - sx, ry = pv.y - sy, rz = pv.z - sz;
        float dd = sqrtf(rx * rx + ry * ry + rz * rz);
        float srk = 1.f / (1.f + expf(alpha * dd - beta));
        S += srk;
        float nxv = rx * inr, nyv = ry * inr, nzv = rz * inr;
        float m1c[16];
#pragma unroll
        for (int j = 0; j < 16; j++) {
            float y = fc1[j * 3] * nxv + fc1[j * 3 + 1] * nyv + fc1[j * 3 + 2] * nzv;
            m1c[j] = fmaxf(y * sc1[j] + bi1[j], 0.f);
            q1m[j] = fmaxf(q1m[j], m1c[j] * srk);
        }
#pragma unroll
        for (int c = 0; c < 16; c++) {
            float g = 0.f;
#pragma unroll
            for (int q = 0; q < 4; q++) {
                float4 v = *(const float4*)(fc2 + c * 32 + q * 4);
                g += v.x * m1c[q * 4] + v.y * m1c[q * 4 + 1] +
                     v.z * m1c[q * 4 + 2] + v.w * m1c[q * 4 + 3];
            }
            G1[c] += g; G2[c] += g * g;
        }
    }
    S += __shfl_xor(S, 1); S += __shfl_xor(S, 2);
#pragma unroll
    for (int j = 0; j < 16; j++) {
        q1m[j] = fmaxf(q1m[j], __shfl_xor(q1m[j], 1));
        q1m[j] = fmaxf(q1m[j], __shfl_xor(q1m[j], 2));
    }
    S = S + (S == 0.f ? 1.f : 0.f) + 1e-6f;
    float fac = 16.f / S;
#pragma unroll
    for (int c = 0; c < 16; c++) {
        float h2 = 0.f;
#pragma unroll
        for (int q = 0; q < 4; q++) {
            float4 v = *(const float4*)(fc2 + c * 32 + 16 + q * 4);
            h2 += v.x * q1m[q * 4] + v.y * q1m[q * 4 + 1] +
                  v.z * q1m[q * 4 + 2] + v.w * q1m[q * 4 + 3];
        }
        h2 *= fac;
        float s2p = G1[c] + 4.f * h2;
        float q2p = G2[c] + 2.f * h2 * G1[c] + 4.f * h2 * h2;
#pragma unroll
        for (int off = 32; off >= 1; off >>= 1) {
            s2p += __shfl_down(s2p, off);
            q2p += __shfl_down(q2p, off);
        }
        if ((t & 63) == 0) {
            red[(t >> 6) * 33 + c] = s2p;
            red[(t >> 6) * 33 + 16 + c] = q2p;
        }
    }
    __syncthreads();
    if (t < 32)
        p2[((size_t)b * 128 + blockIdx.x) * 32 + t] =
            red[t] + red[33 + t] + red[66 + t] + red[99 + t];
}

// ---------------- k_fin: final reduce momp/p2 -> s1,b1,s2,b2 per batch ----------------
__global__ __launch_bounds__(256) void k_fin(const float* __restrict__ momp,
                                             const float* __restrict__ p2,
                                             const float* __restrict__ fc1,
                                             const float* __restrict__ bn1w,
                                             const float* __restrict__ bn1b,
                                             const float* __restrict__ bn2w,
                                             const float* __restrict__ bn2b,
                                             const float* __restrict__ nr_,
                                             float* __restrict__ sb) {
    __shared__ float red[8 * 33], momr[9];
    int b = blockIdx.x, t = threadIdx.x;
    int c = t & 31, ch = t >> 5;
    float s = 0.f;
#pragma unroll
    for (int g = 0; g < 16; g++) s += p2[((size_t)b * 128 + ch * 16 + g) * 32 + c];
    red[ch * 33 + c] = s;
    if (t < 9) {
        float v = 0.f;
#pragma unroll
        for (int g = 0; g < 32; g++) v += momp[(4 * g + b) * 12 + t];
        momr[t] = v;
    }
    __syncthreads();
    if (t < 16) {
        float inv = 1.f / (float)(MM * KK);
        float inr = 1.f / nr_[0];
        float mux = momr[0] * inv * inr, muy = momr[1] * inv * inr, muz = momr[2] * inv * inr;
        float i2 = inv * inr * inr;
        float w0 = fc1[t * 3], wa = fc1[t * 3 + 1], wb = fc1[t * 3 + 2];
        float mean = w0 * mux + wa * muy + wb * muz;
        float ey2 = w0 * w0 * momr[3] * i2 + wa * wa * momr[4] * i2 + wb * wb * momr[5] * i2 +
                    2.f * (w0 * wa * momr[6] * i2 + w0 * wb * momr[7] * i2 + wa * wb * momr[8] * i2);
        float var = fmaxf(ey2 - mean * mean, 0.f);
        float rs = rsqrtf(var + 1e-5f);
        float s1v = bn1w[t] * rs;
        float b1v = bn1b[t] - mean * s1v;
        float sum2 = 0.f, ssq2 = 0.f;
#pragma unroll
        for (int chh = 0; chh < 8; chh++) {
            sum2 += red[chh * 33 + t];
            ssq2 += red[chh * 33 + 16 + t];
        }
        float mean2 = sum2 * inv;
        float var2 = fmaxf(ssq2 * inv - mean2 * mean2, 0.f);
        float rs2 = rsqrtf(var2 + 1e-5f);
        float s2v = bn2w[t] * rs2;
        float b2v = bn2b[t] - mean2 * s2v;
        sb[b * 64 + t] = s1v;
        sb[b * 64 + 16 + t] = b1v;
        sb[b * 64 + 32 + t] = s2v;
        sb[b * 64 + 48 + t] = b2v;
    }
}

// ---------------- k_final: R9 structure + M3 stride 408 + quad-acc stage C ----------------
__global__ __launch_bounds__(256, 3) void k_final(const float* __restrict__ sup,
                                               const int* __restrict__ nbr,
                                               const float* __restrict__ alpha_,
                                               const float* __restrict__ beta_,
                                               const float* __restrict__ nr_,
                                               const float* __restrict__ fc1,
                                               const float* __restrict__ fc2,
                                               const float* __restrict__ fc3,
                                               const float* __restrict__ sb,
                                               const ushort* __restrict__ cvb,
                                               const ushort* __restrict__ xT,
                                               const float* __restrict__ posT,
                                               float* __restrict__ out) {
    __shared__ __align__(16) ushort ov[16 * OV_STRIDE]; // per point: xg[c][k], feat overlay
    __shared__ __align__(16) ushort m3l[16 * M3_STRIDE];// [p][j*24 + k]

    int t = threadIdx.x;
    int b = blockIdx.y;
    int m0 = blockIdx.x * 16;
    int w = t >> 6, l = t & 63;
    int lk = l & 15, kg = l >> 4;
    int ps = t >> 4, ks = t & 15;

    // ---- staging loads issued early ----
    int idxt = nbr[((size_t)b * MM + m0 + ps) * KK + ks];
    float4 pf = *(const float4*)(posT + ((size_t)b * NN + idxt) * 4);
    const ushort8v* xrow = (const ushort8v*)(xT + ((size_t)b * NN + idxt) * 64);
    ushort8v g0 = xrow[0], g1 = xrow[1], g2 = xrow[2], g3 = xrow[3];
    ushort8v g4 = xrow[4], g5 = xrow[5], g6 = xrow[6], g7 = xrow[7];
    float4 w2b0 = *(const float4*)(fc2 + ks * 32 + 16);
    float4 w2b1 = *(const float4*)(fc2 + ks * 32 + 20);
    float4 w2b2 = *(const float4*)(fc2 + ks * 32 + 24);
    float4 w2b3 = *(const float4*)(fc2 + ks * 32 + 28);
    float4 w3b0 = *(const float4*)(fc3 + ks * 32 + 16);
    float4 w3b1 = *(const float4*)(fc3 + ks * 32 + 20);
    float4 w3b2 = *(const float4*)(fc3 + ks * 32 + 24);
    float4 w3b3 = *(const float4*)(fc3 + ks * 32 + 28);

    float alpha = alpha_[0], beta = beta_[0], inr = 1.f / nr_[0];
    const float* sbb = sb + b * 64;

    // ---- phase 1 (fp32): lane = (point ps, neighbor ks) ----
    {
        int mm = m0 + ps;
        float rx = pf.x - sup[((size_t)b * 3 + 0) * MM + mm];
        float ry = pf.y - sup[((size_t)b * 3 + 1) * MM + mm];
        float rz = pf.z - sup[((size_t)b * 3 + 2) * MM + mm];
        float dd = sqrtf(rx * rx + ry * ry + rz * rz);
        float sr = 1.f / (1.f + expf(alpha * dd - beta));
        float S = gsum16(sr);
        S = S + (S == 0.f ? 1.f : 0.f) + 1e-6f;
        float dwk = sr * (16.f / S);
        float nxv = rx * inr, nyv = ry * inr, nzv = rz * inr;

        float m1v[16], mp1[16];
#pragma unroll
        for (int j = 0; j < 16; j++) {
            float y = fc1[j * 3] * nxv + fc1[j * 3 + 1] * nyv + fc1[j * 3 + 2] * nzv;
            m1v[j] = fmaxf(y * sbb[j] + sbb[16 + j], 0.f);
        }
#pragma unroll
        for (int j = 0; j < 16; j++) mp1[j] = gmax16(m1v[j] * dwk);

        float h2own = w2b0.x * mp1[0] + w2b0.y * mp1[1] + w2b0.z * mp1[2] + w2b0.w * mp1[3]
                    + w2b1.x * mp1[4] + w2b1.y * mp1[5] + w2b1.z * mp1[6] + w2b1.w * mp1[7]
                    + w2b2.x * mp1[8] + w2b2.y * mp1[9] + w2b2.z * mp1[10] + w2b2.w * mp1[11]
                    + w2b3.x * mp1[12] + w2b3.y * mp1[13] + w2b3.z * mp1[14] + w2b3.w * mp1[15];
        int pbase = l & 48;
        float m2v[16], mp2[16];
#pragma unroll
        for (int c = 0; c < 16; c++) {
            float a = 0.f;
#pragma unroll
            for (int q = 0; q < 4; q++) {
                float4 v = *(const float4*)(fc2 + c * 32 + q * 4);
                a += v.x * m1v[q * 4] + v.y * m1v[q * 4 + 1] + v.z * m1v[q * 4 + 2] + v.w * m1v[q * 4 + 3];
            }
            a += __shfl(h2own, pbase + c);
            m2v[c] = fmaxf(a * sbb[32 + c] + sbb[48 + c], 0.f);
        }
#pragma unroll
        for (int c = 0; c < 16; c++) mp2[c] = gmax16(m2v[c] * dwk);

        float h3own = w3b0.x * mp2[0] + w3b0.y * mp2[1] + w3b0.z * mp2[2] + w3b0.w * mp2[3]
                    + w3b1.x * mp2[4] + w3b1.y * mp2[5] + w3b1.z * mp2[6] + w3b1.w * mp2[7]
                    + w3b2.x * mp2[8] + w3b2.y * mp2[9] + w3b2.z * mp2[10] + w3b2.w * mp2[11]
                    + w3b3.x * mp2[12] + w3b3.y * mp2[13] + w3b3.z * mp2[14] + w3b3.w * mp2[15];
        ushort* m3p = m3l + ps * M3_STRIDE;
#pragma unroll
        for (int j = 0; j < 16; j++) {
            float a = 0.f;
#pragma unroll
            for (int q = 0; q < 4; q++) {
                float4 v = *(const float4*)(fc3 + j * 32 + q * 4);
                a += v.x * m2v[q * 4] + v.y * m2v[q * 4 + 1] + v.z * m2v[q * 4 + 2] + v.w * m2v[q * 4 + 3];
            }
            a += __shfl(h3own, pbase + j);
            m3p[j * 24 + ks] = f2b(fmaxf(a, 0.f) * dwk);
        }
    }

    // ---- write staged xg rows: ov[p][c*16 + k]  (wave-local) ----
    {
        ushort* ovp = ov + ps * OV_STRIDE;
#define STG(gv, h) _Pragma("unroll") for (int i2 = 0; i2 < 8; i2++) ovp[((h) * 8 + i2) * 16 + ks] = (ushort)gv[i2];
        STG(g0, 0) STG(g1, 1) STG(g2, 2) STG(g3, 3)
        STG(g4, 4) STG(g5, 5) STG(g6, 6) STG(g7, 7)
#undef STG
    }
    // NO barrier: stage B touches only this wave's points

    const f32x4 zz = {0.f, 0.f, 0.f, 0.f};

    // ---- stage B (MFMA, wave-local) ----
#pragma unroll
    for (int pp = 0; pp < 4; pp++) {
        int p = w * 4 + pp;
        bhalf8 afr = {};
        if (kg < 2) afr = __builtin_bit_cast(bhalf8, *(ushort8v*)(m3l + p * M3_STRIDE + lk * 24 + kg * 8));
        ushort* ovb = ov + p * OV_STRIDE;
#pragma unroll
        for (int cb = 0; cb < 4; cb++) {
            bhalf8 bfr = {};
            if (kg < 2) bfr = __builtin_bit_cast(bhalf8, *(ushort8v*)(ovb + (cb * 16 + lk) * 16 + kg * 8));
            f32x4 dF = __builtin_amdgcn_mfma_f32_16x16x32_bf16(afr, bfr, zz, 0, 0, 0);
            ushort4v fw = {f2b(dF[0]), f2b(dF[1]), f2b(dF[2]), f2b(dF[3])};
            *(ushort4v*)(ovb + (cb * 16 + lk) * 16 + kg * 4) = fw;
        }
    }

    // ---- prefetch first 4 stage-C A-fragments ----
    const ushort* arow = cvb + (size_t)(w * 16 + lk) * 1024;
    ushort8v aupre0 = *(const ushort8v*)(arow + 0 * 32 + kg * 8);
    ushort8v aupre1 = *(const ushort8v*)(arow + 1 * 32 + kg * 8);
    ushort8v aupre2 = *(const ushort8v*)(arow + 2 * 32 + kg * 8);
    ushort8v aupre3 = *(const ushort8v*)(arow + 3 * 32 + kg * 8);

    __syncthreads();   // the ONE barrier: stage C reads all points' feat

    // ---- stage C (MFMA): out[o][p] = sum_cj cvb[o][cj] * feat[p][cj]; quad acc ----
    {
        const ushort* brow = ov + lk * OV_STRIDE;
        f32x4 acc0 = zz, acc1 = zz, acc2 = zz, acc3 = zz;
#pragma unroll
        for (int kt = 0; kt < 32; kt += 4) {
            bhalf8 au0, au1;
            if (kt == 0) {
                au0 = __builtin_bit_cast(bhalf8, aupre0);
                au1 = __builtin_bit_cast(bhalf8, aupre1);
            } else {
                au0 = __builtin_bit_cast(bhalf8, *(const ushort8v*)(arow + kt * 32 + kg * 8));
                au1 = __builtin_bit_cast(bhalf8, *(const ushort8v*)(arow + (kt + 1) * 32 + kg * 8));
            }
            bhalf8 au2, au3;
            if (kt == 0) {
                au2 = __builtin_bit_cast(bhalf8, aupre2);
                au3 = __builtin_bit_cast(bhalf8, aupre3);
            } else {
                au2 = __builtin_bit_cast(bhalf8, *(const ushort8v*)(arow + (kt + 2) * 32 + kg * 8));
                au3 = __builtin_bit_cast(bhalf8, *(const ushort8v*)(arow + (kt + 3) * 32 + kg * 8));
            }
            bhalf8 bu0 = __builtin_bit_cast(bhalf8, *(const ushort8v*)(brow + kt * 32 + kg * 8));
            bhalf8 bu1 = __builtin_bit_cast(bhalf8, *(const ushort8v*)(brow + (kt + 1) * 32 + kg * 8));
            bhalf8 bu2 = __builtin_bit_cast(bhalf8, *(const ushort8v*)(brow + (kt + 2) * 32 + kg * 8));
            bhalf8 bu3 = __builtin_bit_cast(bhalf8, *(const ushort8v*)(brow + (kt + 3) * 32 + kg * 8));
            acc0 = __builtin_amdgcn_mfma_f32_16x16x32_bf16(au0, bu0, acc0, 0, 0, 0);
            acc1 = __builtin_amdgcn_mfma_f32_16x16x32_bf16(au1, bu1, acc1, 0, 0, 0);
            acc2 = __builtin_amdgcn_mfma_f32_16x16x32_bf16(au2, bu2, acc2, 0, 0, 0);
            acc3 = __builtin_amdgcn_mfma_f32_16x16x32_bf16(au3, bu3, acc3, 0, 0, 0);
        }
#pragma unroll
        for (int r = 0; r < 4; r++) {
            int o = w * 16 + kg * 4 + r;
            out[((size_t)(b * 64 + o)) * MM + m0 + lk] = (acc0[r] + acc1[r]) + (acc2[r] + acc3[r]);
        }
    }
}

extern "C" void kernel_launch(void* const* d_in, const int* in_sizes, int n_in,
                              void* d_out, int out_size, void* d_ws, size_t ws_size,
                              hipStream_t stream) {
    const float* x    = (const float*)d_in[0];
    const float* pos  = (const float*)d_in[1];
    const float* sup  = (const float*)d_in[2];
    const int*   nbr  = (const int*)d_in[3];
    const float* alp  = (const float*)d_in[4];
    const float* bet  = (const float*)d_in[5];
    const float* nr   = (const float*)d_in[6];
    const float* fc1  = (const float*)d_in[7];
    const float* fc2  = (const float*)d_in[8];
    const float* fc3  = (const float*)d_in[9];
    const float* bn1w = (const float*)d_in[10];
    const float* bn1b = (const float*)d_in[11];
    const float* bn2w = (const float*)d_in[12];
    const float* bn2b = (const float*)d_in[13];
    const float* cv   = (const float*)d_in[14];
    float* out = (float*)d_out;
    ushort* cvb  = (ushort*)((char*)d_ws + WS_CVB_BYTE);
    ushort* xT   = (ushort*)((char*)d_ws + WS_XT_BYTE);
    float*  posT = (float*)((char*)d_ws + WS_PT_BYTE);
    float*  momp = (float*)((char*)d_ws + WS_MOMP_BYTE);
    float*  p2   = (float*)((char*)d_ws + WS_P2_BYTE);
    float*  sb   = (float*)((char*)d_ws + WS_SB_BYTE);

    k_pre<<<704, 256, 0, stream>>>(x, pos, sup, nbr, cv, momp, cvb, xT, posT);
    k_stats2<<<dim3(128, BB), 256, 0, stream>>>(sup, nbr, alp, bet, nr, fc1, fc2,
                                                bn1w, bn1b, posT, momp, p2);
    k_fin<<<BB, 256, 0, stream>>>(momp, p2, fc1, bn1w, bn1b, bn2w, bn2b, nr, sb);
    k_final<<<dim3(512, BB), 256, 0, stream>>>(sup, nbr, alp, bet, nr, fc1, fc2, fc3,
                                               sb, cvb, xT, posT, out);
}

// Round 16
// 87.595 us; speedup vs baseline: 1.1567x; 1.0015x over previous
//
#include <hip/hip_runtime.h>
#include <math.h>

#define BB 4
#define NN 8192
#define MM 8192
#define KK 16

// byte offsets for scratch regions
#define WS_CVB_BYTE  2048                        // 64*1024 ush = 131072 B
#define WS_XT_BYTE   (WS_CVB_BYTE + 131072)      // 4*8192*64 ush = 4194304 B
#define WS_PT_BYTE   (WS_XT_BYTE + 4194304)      // 4*8192*4 f32 = 524288 B
#define WS_MOMP_BYTE (WS_PT_BYTE + 524288)       // 128 blk * 12 f32 = 6144 B
#define WS_P2_BYTE   (WS_MOMP_BYTE + 6144)       // 512 blk * 32 f32 = 65536 B
#define WS_SB_BYTE   (WS_P2_BYTE + 65536)        // 4 * 64 f32 = 1024 B

#define OV_STRIDE 1032   // 2064 B = 16 mod 128: stage-C lk-lanes spread 8 banks (2-way, free)
#define M3_STRIDE 408    // 204 dw = 12 mod 32 (R14: conflicts 1.9M -> 1.64M)

typedef __bf16 bhalf;
typedef bhalf bhalf8 __attribute__((ext_vector_type(8)));
typedef float f32x4 __attribute__((ext_vector_type(4)));
typedef ushort ushort8v __attribute__((ext_vector_type(8)));
typedef ushort ushort4v __attribute__((ext_vector_type(4)));

static __device__ __forceinline__ ushort f2b(float f) {
    return __builtin_bit_cast(ushort, (__bf16)f);
}

// ---- DPP row reductions (16-lane rows), VALU-only: row_ror 1,2,4,8 ----
template <int CTRL>
__device__ __forceinline__ float dpp_rot(float v) {
    int r = __builtin_amdgcn_update_dpp(0, __builtin_bit_cast(int, v), CTRL, 0xF, 0xF, true);
    return __builtin_bit_cast(float, r);
}
__device__ __forceinline__ float gmax16(float v) {
    v = fmaxf(v, dpp_rot<0x121>(v));
    v = fmaxf(v, dpp_rot<0x122>(v));
    v = fmaxf(v, dpp_rot<0x124>(v));
    v = fmaxf(v, dpp_rot<0x128>(v));
    return v;
}
__device__ __forceinline__ float gsum16(float v) {
    v += dpp_rot<0x121>(v);
    v += dpp_rot<0x122>(v);
    v += dpp_rot<0x124>(v);
    v += dpp_rot<0x128>(v);
    return v;
}

// ---------------- k_pre: xT transpose+bf16, posT, cvb, moment partials ----------------
__global__ __launch_bounds__(256) void k_pre(const float* __restrict__ x,
                                             const float* __restrict__ pos,
                                             const float* __restrict__ sup,
                                             const int* __restrict__ nbr,
                                             const float* __restrict__ cv,
                                             float* __restrict__ momp,
                                             ushort* __restrict__ cvb,
                                             ushort* __restrict__ xT,
                                             float* __restrict__ posT) {
    int bid = blockIdx.x, t = threadIdx.x;
    if (bid < 512) {
        int b = bid >> 7, n0 = (bid & 127) * 64;
        __shared__ ushort tile[64 * 66];
        const float* xb = x + (size_t)b * 64 * NN;
#pragma unroll
        for (int i = 0; i < 16; i++) {
            int c = i * 4 + (t >> 6), n = t & 63;
            tile[c * 66 + n] = f2b(xb[(size_t)c * NN + n0 + n]);
        }
        __syncthreads();
#pragma unroll
        for (int i = 0; i < 16; i++) {
            int n = i * 4 + (t >> 6), c = t & 63;
            xT[((size_t)b * NN + n0 + n) * 64 + c] = tile[c * 66 + n];
        }
        int nl = t >> 2, d = t & 3;
        float v = (d < 3) ? pos[((size_t)b * 3 + d) * NN + n0 + nl] : 0.f;
        posT[((size_t)b * NN + n0 + nl) * 4 + d] = v;
    } else if (bid < 576) {
        int e = (bid - 512) * 1024 + t * 4;
        float4 cvv = *(const float4*)(cv + e);
        ushort4v o = {f2b(cvv.x), f2b(cvv.y), f2b(cvv.z), f2b(cvv.w)};
        *(ushort4v*)(cvb + e) = o;
    } else {
        __shared__ float redm[36];
        int rem = bid - 576;
        int b = rem & 3, m = (rem >> 2) * 256 + t;
        const float* posb = pos + (size_t)b * 3 * NN;
        float sx = sup[((size_t)b * 3 + 0) * MM + m];
        float sy = sup[((size_t)b * 3 + 1) * MM + m];
        float sz = sup[((size_t)b * 3 + 2) * MM + m];
        const int* nb = nbr + ((size_t)b * MM + m) * KK;
        float s[9] = {0, 0, 0, 0, 0, 0, 0, 0, 0};
#pragma unroll
        for (int k = 0; k < KK; k++) {
            int id = nb[k];
            float px = posb[id] - sx, py = posb[NN + id] - sy, pz = posb[2 * NN + id] - sz;
            s[0] += px; s[1] += py; s[2] += pz;
            s[3] += px * px; s[4] += py * py; s[5] += pz * pz;
            s[6] += px * py; s[7] += px * pz; s[8] += py * pz;
        }
#pragma unroll
        for (int i = 0; i < 9; i++) {
            float v = s[i];
#pragma unroll
            for (int off = 32; off >= 1; off >>= 1) v += __shfl_down(v, off);
            if ((t & 63) == 0) redm[(t >> 6) * 9 + i] = v;
        }
        __syncthreads();
        if (t < 9) momp[rem * 12 + t] = redm[t] + redm[9 + t] + redm[18 + t] + redm[27 + t];
    }
}

// ---------------- k_stats2: per-(b,c) stats partials, zero atomics, scalar weights ----
__global__ __launch_bounds__(256) void k_stats2(const float* __restrict__ sup,
                                                const int* __restrict__ nbr,
                                                const float* __restrict__ alpha_,
                                                const float* __restrict__ beta_,
                                                const float* __restrict__ nr_,
                                                const float* __restrict__ fc1,
                                                const float* __restrict__ fc2,
                                                const float* __restrict__ bn1w,
                                                const float* __restrict__ bn1b,
                                                const float* __restrict__ posT,
                                                const float* __restrict__ momp,
                                                float* __restrict__ p2) {
    __shared__ float sc1[16], bi1[16], momr[9], red[4 * 33];
    int t = threadIdx.x, b = blockIdx.y;
    if (t < 9) {
        float s = 0.f;
#pragma unroll
        for (int g = 0; g < 32; g++) s += momp[(4 * g + b) * 12 + t];
        momr[t] = s;
    }
    __syncthreads();
    if (t < 16) {
        float inv = 1.f / (float)(MM * KK);
        float inr = 1.f / nr_[0];
        float mux = momr[0] * inv * inr, muy = momr[1] * inv * inr, muz = momr[2] * inv * inr;
        float i2 = inv * inr * inr;
        float w0 = fc1[t * 3], w1v = fc1[t * 3 + 1], w2v = fc1[t * 3 + 2];
        float mean = w0 * mux + w1v * muy + w2v * muz;
        float ey2 = w0 * w0 * momr[3] * i2 + w1v * w1v * momr[4] * i2 + w2v * w2v * momr[5] * i2 +
                    2.f * (w0 * w1v * momr[6] * i2 + w0 * w2v * momr[7] * i2 + w1v * w2v * momr[8] * i2);
        float var = fmaxf(ey2 - mean * mean, 0.f);
        float rs = rsqrtf(var + 1e-5f);
        sc1[t] = bn1w[t] * rs;
        bi1[t] = bn1b[t] - mean * sc1[t];
    }
    __syncthreads();
    int mi = t >> 2, kq = t & 3;
    int m = blockIdx.x * 64 + mi;
    float alpha = alpha_[0], beta = beta_[0], inr = 1.f / nr_[0];
    float sx = sup[((size_t)b * 3 + 0) * MM + m];
    float sy = sup[((size_t)b * 3 + 1) * MM + m];
    float sz = sup[((size_t)b * 3 + 2) * MM + m];
    const int* nb = nbr + ((size_t)b * MM + m) * KK + kq * 4;

    float q1m[16], G1[16], G2[16];
#pragma unroll
    for (int j = 0; j < 16; j++) { q1m[j] = 0.f; G1[j] = 0.f; G2[j] = 0.f; }
    float S = 0.f;
#pragma unroll
    for (int kk = 0; kk < 4; kk++) {
        int id = nb[kk];
        float4 pv = *(const float4*)(posT + ((size_t)b * NN + id) * 4);
        float rx = pv.x - sx, ry = pv.y - sy, rz = pv.z - sz;
        float dd = sqrtf(rx * rx + ry * ry + rz * rz);
        float srk = 1.f / (1.f + expf(alpha * dd - beta));
        S += srk;
        float nxv = rx * inr, nyv = ry * inr, nzv = rz * inr;
        float m1c[16];
#pragma unroll
        for (int j = 0; j < 16; j++) {
            float y = fc1[j * 3] * nxv + fc1[j * 3 + 1] * nyv + fc1[j * 3 + 2] * nzv;
            m1c[j] = fmaxf(y * sc1[j] + bi1[j], 0.f);
            q1m[j] = fmaxf(q1m[j], m1c[j] * srk);
        }
#pragma unroll
        for (int c = 0; c < 16; c++) {
            float g = 0.f;
#pragma unroll
            for (int q = 0; q < 4; q++) {
                float4 v = *(const float4*)(fc2 + c * 32 + q * 4);
                g += v.x * m1c[q * 4] + v.y * m1c[q * 4 + 1] +
                     v.z * m1c[q * 4 + 2] + v.w * m1c[q * 4 + 3];
            }
            G1[c] += g; G2[c] += g * g;
        }
    }
    S += __shfl_xor(S, 1); S += __shfl_xor(S, 2);
#pragma unroll
    for (int j = 0; j < 16; j++) {
        q1m[j] = fmaxf(q1m[j], __shfl_xor(q1m[j], 1));
        q1m[j] = fmaxf(q1m[j], __shfl_xor(q1m[j], 2));
    }
    S = S + (S == 0.f ? 1.f : 0.f) + 1e-6f;
    float fac = 16.f / S;
#pragma unroll
    for (int c = 0; c < 16; c++) {
        float h2 = 0.f;
#pragma unroll
        for (int q = 0; q < 4; q++) {
            float4 v = *(const float4*)(fc2 + c * 32 + 16 + q * 4);
            h2 += v.x * q1m[q * 4] + v.y * q1m[q * 4 + 1] +
                  v.z * q1m[q * 4 + 2] + v.w * q1m[q * 4 + 3];
        }
        h2 *= fac;
        float s2p = G1[c] + 4.f * h2;
        float q2p = G2[c] + 2.f * h2 * G1[c] + 4.f * h2 * h2;
#pragma unroll
        for (int off = 32; off >= 1; off >>= 1) {
            s2p += __shfl_down(s2p, off);
            q2p += __shfl_down(q2p, off);
        }
        if ((t & 63) == 0) {
            red[(t >> 6) * 33 + c] = s2p;
            red[(t >> 6) * 33 + 16 + c] = q2p;
        }
    }
    __syncthreads();
    if (t < 32)
        p2[((size_t)b * 128 + blockIdx.x) * 32 + t] =
            red[t] + red[33 + t] + red[66 + t] + red[99 + t];
}

// ---------------- k_fin: final reduce momp/p2 -> s1,b1,s2,b2 per batch ----------------
__global__ __launch_bounds__(256) void k_fin(const float* __restrict__ momp,
                                             const float* __restrict__ p2,
                                             const float* __restrict__ fc1,
                                             const float* __restrict__ bn1w,
                                             const float* __restrict__ bn1b,
                                             const float* __restrict__ bn2w,
                                             const float* __restrict__ bn2b,
                                             const float* __restrict__ nr_,
                                             float* __restrict__ sb) {
    __shared__ float red[8 * 33], momr[9];
    int b = blockIdx.x, t = threadIdx.x;
    int c = t & 31, ch = t >> 5;
    float s = 0.f;
#pragma unroll
    for (int g = 0; g < 16; g++) s += p2[((size_t)b * 128 + ch * 16 + g) * 32 + c];
    red[ch * 33 + c] = s;
    if (t < 9) {
        float v = 0.f;
#pragma unroll
        for (int g = 0; g < 32; g++) v += momp[(4 * g + b) * 12 + t];
        momr[t] = v;
    }
    __syncthreads();
    if (t < 16) {
        float inv = 1.f / (float)(MM * KK);
        float inr = 1.f / nr_[0];
        float mux = momr[0] * inv * inr, muy = momr[1] * inv * inr, muz = momr[2] * inv * inr;
        float i2 = inv * inr * inr;
        float w0 = fc1[t * 3], wa = fc1[t * 3 + 1], wb = fc1[t * 3 + 2];
        float mean = w0 * mux + wa * muy + wb * muz;
        float ey2 = w0 * w0 * momr[3] * i2 + wa * wa * momr[4] * i2 + wb * wb * momr[5] * i2 +
                    2.f * (w0 * wa * momr[6] * i2 + w0 * wb * momr[7] * i2 + wa * wb * momr[8] * i2);
        float var = fmaxf(ey2 - mean * mean, 0.f);
        float rs = rsqrtf(var + 1e-5f);
        float s1v = bn1w[t] * rs;
        float b1v = bn1b[t] - mean * s1v;
        float sum2 = 0.f, ssq2 = 0.f;
#pragma unroll
        for (int chh = 0; chh < 8; chh++) {
            sum2 += red[chh * 33 + t];
            ssq2 += red[chh * 33 + 16 + t];
        }
        float mean2 = sum2 * inv;
        float var2 = fmaxf(ssq2 * inv - mean2 * mean2, 0.f);
        float rs2 = rsqrtf(var2 + 1e-5f);
        float s2v = bn2w[t] * rs2;
        float b2v = bn2b[t] - mean2 * s2v;
        sb[b * 64 + t] = s1v;
        sb[b * 64 + 16 + t] = b1v;
        sb[b * 64 + 32 + t] = s2v;
        sb[b * 64 + 48 + t] = b2v;
    }
}

// ---------------- k_final: R15 structure, OV_STRIDE 1032 (stage-C conflict fix) ----------
__global__ __launch_bounds__(256, 3) void k_final(const float* __restrict__ sup,
                                               const int* __restrict__ nbr,
                                               const float* __restrict__ alpha_,
                                               const float* __restrict__ beta_,
                                               const float* __restrict__ nr_,
                                               const float* __restrict__ fc1,
                                               const float* __restrict__ fc2,
                                               const float* __restrict__ fc3,
                                               const float* __restrict__ sb,
                                               const ushort* __restrict__ cvb,
                                               const ushort* __restrict__ xT,
                                               const float* __restrict__ posT,
                                               float* __restrict__ out) {
    __shared__ __align__(16) ushort ov[16 * OV_STRIDE]; // per point: xg[c][k], feat overlay
    __shared__ __align__(16) ushort m3l[16 * M3_STRIDE];// [p][j*24 + k]

    int t = threadIdx.x;
    int b = blockIdx.y;
    int m0 = blockIdx.x * 16;
    int w = t >> 6, l = t & 63;
    int lk = l & 15, kg = l >> 4;
    int ps = t >> 4, ks = t & 15;

    // ---- staging loads issued early ----
    int idxt = nbr[((size_t)b * MM + m0 + ps) * KK + ks];
    float4 pf = *(const float4*)(posT + ((size_t)b * NN + idxt) * 4);
    const ushort8v* xrow = (const ushort8v*)(xT + ((size_t)b * NN + idxt) * 64);
    ushort8v g0 = xrow[0], g1 = xrow[1], g2 = xrow[2], g3 = xrow[3];
    ushort8v g4 = xrow[4], g5 = xrow[5], g6 = xrow[6], g7 = xrow[7];
    float4 w2b0 = *(const float4*)(fc2 + ks * 32 + 16);
    float4 w2b1 = *(const float4*)(fc2 + ks * 32 + 20);
    float4 w2b2 = *(const float4*)(fc2 + ks * 32 + 24);
    float4 w2b3 = *(const float4*)(fc2 + ks * 32 + 28);
    float4 w3b0 = *(const float4*)(fc3 + ks * 32 + 16);
    float4 w3b1 = *(const float4*)(fc3 + ks * 32 + 20);
    float4 w3b2 = *(const float4*)(fc3 + ks * 32 + 24);
    float4 w3b3 = *(const float4*)(fc3 + ks * 32 + 28);

    float alpha = alpha_[0], beta = beta_[0], inr = 1.f / nr_[0];
    const float* sbb = sb + b * 64;

    // ---- phase 1 (fp32): lane = (point ps, neighbor ks) ----
    {
        int mm = m0 + ps;
        float rx = pf.x - sup[((size_t)b * 3 + 0) * MM + mm];
        float ry = pf.y - sup[((size_t)b * 3 + 1) * MM + mm];
        float rz = pf.z - sup[((size_t)b * 3 + 2) * MM + mm];
        float dd = sqrtf(rx * rx + ry * ry + rz * rz);
        float sr = 1.f / (1.f + expf(alpha * dd - beta));
        float S = gsum16(sr);
        S = S + (S == 0.f ? 1.f : 0.f) + 1e-6f;
        float dwk = sr * (16.f / S);
        float nxv = rx * inr, nyv = ry * inr, nzv = rz * inr;

        float m1v[16], mp1[16];
#pragma unroll
        for (int j = 0; j < 16; j++) {
            float y = fc1[j * 3] * nxv + fc1[j * 3 + 1] * nyv + fc1[j * 3 + 2] * nzv;
            m1v[j] = fmaxf(y * sbb[j] + sbb[16 + j], 0.f);
        }
#pragma unroll
        for (int j = 0; j < 16; j++) mp1[j] = gmax16(m1v[j] * dwk);

        float h2own = w2b0.x * mp1[0] + w2b0.y * mp1[1] + w2b0.z * mp1[2] + w2b0.w * mp1[3]
                    + w2b1.x * mp1[4] + w2b1.y * mp1[5] + w2b1.z * mp1[6] + w2b1.w * mp1[7]
                    + w2b2.x * mp1[8] + w2b2.y * mp1[9] + w2b2.z * mp1[10] + w2b2.w * mp1[11]
                    + w2b3.x * mp1[12] + w2b3.y * mp1[13] + w2b3.z * mp1[14] + w2b3.w * mp1[15];
        int pbase = l & 48;
        float m2v[16], mp2[16];
#pragma unroll
        for (int c = 0; c < 16; c++) {
            float a = 0.f;
#pragma unroll
            for (int q = 0; q < 4; q++) {
                float4 v = *(const float4*)(fc2 + c * 32 + q * 4);
                a += v.x * m1v[q * 4] + v.y * m1v[q * 4 + 1] + v.z * m1v[q * 4 + 2] + v.w * m1v[q * 4 + 3];
            }
            a += __shfl(h2own, pbase + c);
            m2v[c] = fmaxf(a * sbb[32 + c] + sbb[48 + c], 0.f);
        }
#pragma unroll
        for (int c = 0; c < 16; c++) mp2[c] = gmax16(m2v[c] * dwk);

        float h3own = w3b0.x * mp2[0] + w3b0.y * mp2[1] + w3b0.z * mp2[2] + w3b0.w * mp2[3]
                    + w3b1.x * mp2[4] + w3b1.y * mp2[5] + w3b1.z * mp2[6] + w3b1.w * mp2[7]
                    + w3b2.x * mp2[8] + w3b2.y * mp2[9] + w3b2.z * mp2[10] + w3b2.w * mp2[11]
                    + w3b3.x * mp2[12] + w3b3.y * mp2[13] + w3b3.z * mp2[14] + w3b3.w * mp2[15];
        ushort* m3p = m3l + ps * M3_STRIDE;
#pragma unroll
        for (int j = 0; j < 16; j++) {
            float a = 0.f;
#pragma unroll
            for (int q = 0; q < 4; q++) {
                float4 v = *(const float4*)(fc3 + j * 32 + q * 4);
                a += v.x * m2v[q * 4] + v.y * m2v[q * 4 + 1] + v.z * m2v[q * 4 + 2] + v.w * m2v[q * 4 + 3];
            }
            a += __shfl(h3own, pbase + j);
            m3p[j * 24 + ks] = f2b(fmaxf(a, 0.f) * dwk);
        }
    }

    // ---- write staged xg rows: ov[p][c*16 + k]  (wave-local) ----
    {
        ushort* ovp = ov + ps * OV_STRIDE;
#define STG(gv, h) _Pragma("unroll") for (int i2 = 0; i2 < 8; i2++) ovp[((h) * 8 + i2) * 16 + ks] = (ushort)gv[i2];
        STG(g0, 0) STG(g1, 1) STG(g2, 2) STG(g3, 3)
        STG(g4, 4) STG(g5, 5) STG(g6, 6) STG(g7, 7)
#undef STG
    }
    // NO barrier: stage B touches only this wave's points

    const f32x4 zz = {0.f, 0.f, 0.f, 0.f};

    // ---- stage B (MFMA, wave-local) ----
#pragma unroll
    for (int pp = 0; pp < 4; pp++) {
        int p = w * 4 + pp;
        bhalf8 afr = {};
        if (kg < 2) afr = __builtin_bit_cast(bhalf8, *(ushort8v*)(m3l + p * M3_STRIDE + lk * 24 + kg * 8));
        ushort* ovb = ov + p * OV_STRIDE;
#pragma unroll
        for (int cb = 0; cb < 4; cb++) {
            bhalf8 bfr = {};
            if (kg < 2) bfr = __builtin_bit_cast(bhalf8, *(ushort8v*)(ovb + (cb * 16 + lk) * 16 + kg * 8));
            f32x4 dF = __builtin_amdgcn_mfma_f32_16x16x32_bf16(afr, bfr, zz, 0, 0, 0);
            ushort4v fw = {f2b(dF[0]), f2b(dF[1]), f2b(dF[2]), f2b(dF[3])};
            *(ushort4v*)(ovb + (cb * 16 + lk) * 16 + kg * 4) = fw;
        }
    }

    // ---- prefetch first 4 stage-C A-fragments ----
    const ushort* arow = cvb + (size_t)(w * 16 + lk) * 1024;
    ushort8v aupre0 = *(const ushort8v*)(arow + 0 * 32 + kg * 8);
    ushort8v aupre1 = *(const ushort8v*)(arow + 1 * 32 + kg * 8);
    ushort8v aupre2 = *(const ushort8v*)(arow + 2 * 32 + kg * 8);
    ushort8v aupre3 = *(const ushort8v*)(arow + 3 * 32 + kg * 8);

    __syncthreads();   // the ONE barrier: stage C reads all points' feat

    // ---- stage C (MFMA): out[o][p] = sum_cj cvb[o][cj] * feat[p][cj]; quad acc ----
    {
        const ushort* brow = ov + lk * OV_STRIDE;
        f32x4 acc0 = zz, acc1 = zz, acc2 = zz, acc3 = zz;
#pragma unroll
        for (int kt = 0; kt < 32; kt += 4) {
            bhalf8 au0, au1;
            if (kt == 0) {
                au0 = __builtin_bit_cast(bhalf8, aupre0);
                au1 = __builtin_bit_cast(bhalf8, aupre1);
            } else {
                au0 = __builtin_bit_cast(bhalf8, *(const ushort8v*)(arow + kt * 32 + kg * 8));
                au1 = __builtin_bit_cast(bhalf8, *(const ushort8v*)(arow + (kt + 1) * 32 + kg * 8));
            }
            bhalf8 au2, au3;
            if (kt == 0) {
                au2 = __builtin_bit_cast(bhalf8, aupre2);
                au3 = __builtin_bit_cast(bhalf8, aupre3);
            } else {
                au2 = __builtin_bit_cast(bhalf8, *(const ushort8v*)(arow + (kt + 2) * 32 + kg * 8));
                au3 = __builtin_bit_cast(bhalf8, *(const ushort8v*)(arow + (kt + 3) * 32 + kg * 8));
            }
            bhalf8 bu0 = __builtin_bit_cast(bhalf8, *(const ushort8v*)(brow + kt * 32 + kg * 8));
            bhalf8 bu1 = __builtin_bit_cast(bhalf8, *(const ushort8v*)(brow + (kt + 1) * 32 + kg * 8));
            bhalf8 bu2 = __builtin_bit_cast(bhalf8, *(const ushort8v*)(brow + (kt + 2) * 32 + kg * 8));
            bhalf8 bu3 = __builtin_bit_cast(bhalf8, *(const ushort8v*)(brow + (kt + 3) * 32 + kg * 8));
            acc0 = __builtin_amdgcn_mfma_f32_16x16x32_bf16(au0, bu0, acc0, 0, 0, 0);
            acc1 = __builtin_amdgcn_mfma_f32_16x16x32_bf16(au1, bu1, acc1, 0, 0, 0);
            acc2 = __builtin_amdgcn_mfma_f32_16x16x32_bf16(au2, bu2, acc2, 0, 0, 0);
            acc3 = __builtin_amdgcn_mfma_f32_16x16x32_bf16(au3, bu3, acc3, 0, 0, 0);
        }
#pragma unroll
        for (int r = 0; r < 4; r++) {
            int o = w * 16 + kg * 4 + r;
            out[((size_t)(b * 64 + o)) * MM + m0 + lk] = (acc0[r] + acc1[r]) + (acc2[r] + acc3[r]);
        }
    }
}

extern "C" void kernel_launch(void* const* d_in, const int* in_sizes, int n_in,
                              void* d_out, int out_size, void* d_ws, size_t ws_size,
                              hipStream_t stream) {
    const float* x    = (const float*)d_in[0];
    const float* pos  = (const float*)d_in[1];
    const float* sup  = (const float*)d_in[2];
    const int*   nbr  = (const int*)d_in[3];
    const float* alp  = (const float*)d_in[4];
    const float* bet  = (const float*)d_in[5];
    const float* nr   = (const float*)d_in[6];
    const float* fc1  = (const float*)d_in[7];
    const float* fc2  = (const float*)d_in[8];
    const float* fc3  = (const float*)d_in[9];
    const float* bn1w = (const float*)d_in[10];
    const float* bn1b = (const float*)d_in[11];
    const float* bn2w = (const float*)d_in[12];
    const float* bn2b = (const float*)d_in[13];
    const float* cv   = (const float*)d_in[14];
    float* out = (float*)d_out;
    ushort* cvb  = (ushort*)((char*)d_ws + WS_CVB_BYTE);
    ushort* xT   = (ushort*)((char*)d_ws + WS_XT_BYTE);
    float*  posT = (float*)((char*)d_ws + WS_PT_BYTE);
    float*  momp = (float*)((char*)d_ws + WS_MOMP_BYTE);
    float*  p2   = (float*)((char*)d_ws + WS_P2_BYTE);
    float*  sb   = (float*)((char*)d_ws + WS_SB_BYTE);

    k_pre<<<704, 256, 0, stream>>>(x, pos, sup, nbr, cv, momp, cvb, xT, posT);
    k_stats2<<<dim3(128, BB), 256, 0, stream>>>(sup, nbr, alp, bet, nr, fc1, fc2,
                                                bn1w, bn1b, posT, momp, p2);
    k_fin<<<BB, 256, 0, stream>>>(momp, p2, fc1, bn1w, bn1b, bn2w, bn2b, nr, sb);
    k_final<<<dim3(512, BB), 256, 0, stream>>>(sup, nbr, alp, bet, nr, fc1, fc2, fc3,
                                               sb, cvb, xT, posT, out);
}